// Round 16
// baseline (161.260 us; speedup 1.0000x reference)
//
#include <hip/hip_runtime.h>
#include <math.h>

// Problem constants
constexpr int BATCH = 16384;
constexpr int IND   = 2048;   // INPUT
constexpr int HID   = 32;     // HIDDEN
constexpr int OUTD  = 512;    // OUTPUT

constexpr int NC1 = 128;      // corr1/xsum partial slices (b-chunks of 128)
constexpr int NSA = 512;      // actsum partial slices (k_act blocks)
constexpr int NC2 = 256;      // corr2 b-chunks (64 b each)

constexpr int SA  = 136;      // bf16 row stride, k_act tiles (128 k + pad)
constexpr int SB2 = 136;      // bf16 row stride, k_corr1 tiles (128 b + pad)

typedef __attribute__((ext_vector_type(8))) short bf16x8;
typedef __attribute__((ext_vector_type(4))) float f32x4;

__device__ __forceinline__ unsigned short f2bf(float f) {
  unsigned u = __float_as_uint(f);
  u += 0x7FFFu + ((u >> 16) & 1u);          // round-to-nearest-even
  return (unsigned short)(u >> 16);
}
__device__ __forceinline__ float bf2f(unsigned short h) {
  return __uint_as_float(((unsigned)h) << 16);
}
__device__ __forceinline__ void split2(float f, unsigned short& hi,
                                       unsigned short& lo) {
  hi = f2bf(f);
  lo = f2bf(f - bf2f(hi));
}

#define UPD4(C, A, S)                 \
  (C).x = fmaf((S), (A).x, (C).x);    \
  (C).y = fmaf((S), (A).y, (C).y);    \
  (C).z = fmaf((S), (A).z, (C).z);    \
  (C).w = fmaf((S), (A).w, (C).w);

#define DOT4(Z, A, W)                 \
  (Z) = fmaf((A).x, (W).x, (Z));      \
  (Z) = fmaf((A).y, (W).y, (Z));      \
  (Z) = fmaf((A).z, (W).z, (Z));      \
  (Z) = fmaf((A).w, (W).w, (Z));

// ---------------------------------------------------------------------------
// K1a: act = relu(x @ w1T), split-bf16 MFMA (r14-verified). SPLIT from the
// fused k_l1: r15 showed the 113KB mega-kernel pins grid=256 = 1 blk/CU,
// where no inter-block TLP exists and dbuf can't compensate (84->80us only).
// Now 32 rows/block, 35.8KB LDS, grid 512 = 2 blk/CU. Staging is
// issue-early/write-late: regs carry the next chunk across the barrier.
// Also emits actT bf16 [h][b] (global, 1MB) for k_corr1's B/A operands.
// ---------------------------------------------------------------------------
__global__ __launch_bounds__(256, 2) void k_act(
    const float* __restrict__ x, const float* __restrict__ w1,
    float* __restrict__ act, unsigned short* __restrict__ actT,
    float* __restrict__ actsum_part) {
  const int tid = threadIdx.x;
  const int blk = blockIdx.x;              // 0..511
  const int b0 = blk * 32;
  const int lane = tid & 63;
  const int wv = tid >> 6;                 // 0..3
  const int arow = lane & 15;
  const int m4 = lane >> 4;                // 0..3
  const int ksub = m4 * 8;
  const int rt = wv & 1;                   // row-tile (16 rows)
  const int ht = wv >> 1;                  // h-tile

  __shared__ __align__(16) char smem[35840];
  unsigned short* const XH = (unsigned short*)(smem);          // 32 x SA
  unsigned short* const XL = (unsigned short*)(smem + 8704);
  unsigned short* const WH = (unsigned short*)(smem + 17408);
  unsigned short* const WL = (unsigned short*)(smem + 26112);
  float (*asum_s)[8] = (float(*)[8])(smem + 34816);

  const int rp = tid >> 4;                 // 0..15 -> rows 2rp, 2rp+1
  const int kg = (tid & 15) * 8;

  float4 px0a, px0b, px1a, px1b, pw0a, pw0b, pw1a, pw1b;

#define LOADA(K0)                                                    \
  {                                                                  \
    const float* xr0 = x + (size_t)(b0 + 2 * rp) * IND + (K0) + kg;  \
    const float* xr1 = xr0 + IND;                                    \
    px0a = *(const float4*)(xr0);                                    \
    px0b = *(const float4*)(xr0 + 4);                                \
    px1a = *(const float4*)(xr1);                                    \
    px1b = *(const float4*)(xr1 + 4);                                \
    const float* wr0 = w1 + (size_t)(2 * rp) * IND + (K0) + kg;      \
    const float* wr1 = wr0 + IND;                                    \
    pw0a = *(const float4*)(wr0);                                    \
    pw0b = *(const float4*)(wr0 + 4);                                \
    pw1a = *(const float4*)(wr1);                                    \
    pw1b = *(const float4*)(wr1 + 4);                                \
  }

#define PUT4(DSTH, DSTL, ROW, COL, V)                                \
  {                                                                  \
    ushort4 h_, l_;                                                  \
    split2((V).x, h_.x, l_.x); split2((V).y, h_.y, l_.y);            \
    split2((V).z, h_.z, l_.z); split2((V).w, h_.w, l_.w);            \
    *(ushort4*)(&(DSTH)[(ROW) * SA + (COL)]) = h_;                   \
    *(ushort4*)(&(DSTL)[(ROW) * SA + (COL)]) = l_;                   \
  }

#define STOREA                                                       \
  {                                                                  \
    PUT4(XH, XL, 2 * rp, kg, px0a);                                  \
    PUT4(XH, XL, 2 * rp, kg + 4, px0b);                              \
    PUT4(XH, XL, 2 * rp + 1, kg, px1a);                              \
    PUT4(XH, XL, 2 * rp + 1, kg + 4, px1b);                          \
    PUT4(WH, WL, 2 * rp, kg, pw0a);                                  \
    PUT4(WH, WL, 2 * rp, kg + 4, pw0b);                              \
    PUT4(WH, WL, 2 * rp + 1, kg, pw1a);                              \
    PUT4(WH, WL, 2 * rp + 1, kg + 4, pw1b);                          \
  }

  f32x4 accA = {0.f, 0.f, 0.f, 0.f};
  LOADA(0);

  for (int kc = 0; kc < 16; ++kc) {
    __syncthreads();                       // prev chunk's readers done
    STOREA;
    __syncthreads();                       // tiles visible
    if (kc < 15) LOADA((kc + 1) * 128);    // issue next loads EARLY
#pragma unroll
    for (int ks = 0; ks < 4; ++ks) {
      const int kk = ks * 32 + ksub;
      bf16x8 ah = *(const bf16x8*)(&XH[(rt * 16 + arow) * SA + kk]);
      bf16x8 al = *(const bf16x8*)(&XL[(rt * 16 + arow) * SA + kk]);
      bf16x8 bh = *(const bf16x8*)(&WH[(ht * 16 + arow) * SA + kk]);
      bf16x8 bl_ = *(const bf16x8*)(&WL[(ht * 16 + arow) * SA + kk]);
      accA = __builtin_amdgcn_mfma_f32_16x16x32_bf16(ah, bh, accA, 0, 0, 0);
      accA = __builtin_amdgcn_mfma_f32_16x16x32_bf16(ah, bl_, accA, 0, 0, 0);
      accA = __builtin_amdgcn_mfma_f32_16x16x32_bf16(al, bh, accA, 0, 0, 0);
    }
  }

#pragma unroll
  for (int r = 0; r < 4; ++r) accA[r] = fmaxf(accA[r], 0.f);

  // C layout: col=lane&15 (h in tile), row=m4*4+r (b in tile)  [m89-verified]
  const int bl = rt * 16 + (m4 << 2);
  const int h = ht * 16 + arow;
#pragma unroll
  for (int r = 0; r < 4; ++r)
    act[(size_t)(b0 + bl + r) * HID + h] = accA[r];
  {
    ushort4 pa;
    pa.x = f2bf(accA[0]); pa.y = f2bf(accA[1]);
    pa.z = f2bf(accA[2]); pa.w = f2bf(accA[3]);
    *(ushort4*)(&actT[(size_t)h * BATCH + b0 + bl]) = pa;
  }
  asum_s[h][rt * 4 + m4] = accA[0] + accA[1] + accA[2] + accA[3];
  __syncthreads();
  if (tid < 32) {
    float s = 0.f;
#pragma unroll
    for (int q = 0; q < 8; ++q) s += asum_s[tid][q];
    actsum_part[blk * HID + tid] = s;
  }
}

// ---------------------------------------------------------------------------
// K1b: corr1T_part[bc][j][i] = sum_{b in chunk} x[b,i]*act[b,j]; xsum via
// ones-constant B-fragment. Plain bf16 MFMA (w1_new normalization tolerates).
// grid = 512 = (bc 0..127 b-chunks of 128) x (iq 0..3 i-quadrants of 512).
// 512 thr (8 waves; wave = one 16-i tile per i-subchunk). x^T staged bf16
// with the r14-verified XOR swizzle (phys_b = b ^ ((i>>3)&7)*8); actT read
// coalesced from global (written by k_act). 43.5KB LDS -> 2+ blk/CU.
// ---------------------------------------------------------------------------
__global__ __launch_bounds__(512, 2) void k_corr1(
    const float* __restrict__ x, const unsigned short* __restrict__ actT,
    float* __restrict__ corr1T_part, float* __restrict__ xsum_part) {
  const int tid = threadIdx.x;
  const int bc = blockIdx.x >> 2;          // 0..127
  const int iq = blockIdx.x & 3;           // 0..3
  const int b0 = bc * 128;
  const int ibase = iq * 512;
  const int lane = tid & 63;
  const int wv = tid >> 6;                 // 0..7
  const int arow = lane & 15;
  const int m4 = lane >> 4;
  const int ksub = m4 * 8;
  const int it = wv * 16;                  // wave's i-tile base in chunk

  __shared__ __align__(16) char smem[43520];
  unsigned short* const XT = (unsigned short*)(smem);          // 128 x SB2
  unsigned short* const AT = (unsigned short*)(smem + 34816);  // 32 x SB2

  // stage actT tile [32][128] once (coalesced ushort8 rows)
  {
    const int hrow = tid >> 4;             // 0..31
    const int boff = (tid & 15) * 8;       // 0..120
    *(bf16x8*)(&AT[hrow * SB2 + boff]) =
        *(const bf16x8*)(&actT[(size_t)hrow * BATCH + b0 + boff]);
  }

  const short one_bf = (short)0x3F80;
  const bf16x8 ones = {one_bf, one_bf, one_bf, one_bf,
                       one_bf, one_bf, one_bf, one_bf};

  const int ig = tid & 15;                 // i-group (8 i)
  const int bq = (tid >> 4) & 15;          // b-pair index
  const int half = tid >> 8;               // 0..1
  const int s0 = 2 * half, s1 = 2 * half + 1;  // b-32-subchunks

  float4 xa0, xb0, ya0, yb0, xa1, xb1, ya1, yb1;

#define LOADC(IC)                                                           \
  {                                                                         \
    const int icol = ibase + (IC) * 128 + ig * 8;                           \
    const float* r0 = x + (size_t)(b0 + 32 * s0 + 2 * bq) * IND + icol;     \
    const float* r1 = r0 + IND;                                             \
    xa0 = *(const float4*)(r0); xb0 = *(const float4*)(r0 + 4);             \
    ya0 = *(const float4*)(r1); yb0 = *(const float4*)(r1 + 4);             \
    const float* r2 = x + (size_t)(b0 + 32 * s1 + 2 * bq) * IND + icol;     \
    const float* r3 = r2 + IND;                                             \
    xa1 = *(const float4*)(r2); xb1 = *(const float4*)(r2 + 4);             \
    ya1 = *(const float4*)(r3); yb1 = *(const float4*)(r3 + 4);             \
  }

#define STC(SUB, XA, XB, YA, YB)                                            \
  {                                                                         \
    const int qb = (32 * (SUB) + 2 * bq) ^ ((ig & 7) * 8);                  \
    unsigned short* basew = &XT[(size_t)(ig * 8) * SB2 + qb];               \
    ushort2 p;                                                              \
    p.x = f2bf((XA).x); p.y = f2bf((YA).x); *(ushort2*)(basew + 0 * SB2) = p; \
    p.x = f2bf((XA).y); p.y = f2bf((YA).y); *(ushort2*)(basew + 1 * SB2) = p; \
    p.x = f2bf((XA).z); p.y = f2bf((YA).z); *(ushort2*)(basew + 2 * SB2) = p; \
    p.x = f2bf((XA).w); p.y = f2bf((YA).w); *(ushort2*)(basew + 3 * SB2) = p; \
    p.x = f2bf((XB).x); p.y = f2bf((YB).x); *(ushort2*)(basew + 4 * SB2) = p; \
    p.x = f2bf((XB).y); p.y = f2bf((YB).y); *(ushort2*)(basew + 5 * SB2) = p; \
    p.x = f2bf((XB).z); p.y = f2bf((YB).z); *(ushort2*)(basew + 6 * SB2) = p; \
    p.x = f2bf((XB).w); p.y = f2bf((YB).w); *(ushort2*)(basew + 7 * SB2) = p; \
  }

  const int swzr = ((((it + arow) >> 3)) & 7) * 8;

  LOADC(0);
  for (int ic = 0; ic < 4; ++ic) {
    __syncthreads();                       // prev readers done (also AT w0)
    STC(s0, xa0, xb0, ya0, yb0);
    STC(s1, xa1, xb1, ya1, yb1);
    __syncthreads();
    if (ic < 3) LOADC(ic + 1);             // issue next loads EARLY

    f32x4 c00 = {0.f, 0.f, 0.f, 0.f};
    f32x4 c01 = {0.f, 0.f, 0.f, 0.f};
    f32x4 c02 = {0.f, 0.f, 0.f, 0.f};
#pragma unroll
    for (int bs = 0; bs < 4; ++bs) {
      const int bb = bs * 32 + ksub;
      bf16x8 a = *(const bf16x8*)(&XT[(it + arow) * SB2 + (bb ^ swzr)]);
      bf16x8 e0 = *(const bf16x8*)(&AT[arow * SB2 + bb]);
      bf16x8 e1 = *(const bf16x8*)(&AT[(16 + arow) * SB2 + bb]);
      c00 = __builtin_amdgcn_mfma_f32_16x16x32_bf16(a, e0, c00, 0, 0, 0);
      c01 = __builtin_amdgcn_mfma_f32_16x16x32_bf16(a, e1, c01, 0, 0, 0);
      c02 = __builtin_amdgcn_mfma_f32_16x16x32_bf16(a, ones, c02, 0, 0, 0);
    }
    float* basep = corr1T_part + (size_t)bc * (IND * HID);
    const int gi = ibase + ic * 128 + it + (m4 << 2);
    *(f32x4*)(basep + (size_t)arow * IND + gi) = c00;
    *(f32x4*)(basep + (size_t)(16 + arow) * IND + gi) = c01;
    if (arow == 0)
      *(f32x4*)(xsum_part + (size_t)bc * IND + gi) = c02;
  }
}

// ---------------------------------------------------------------------------
// K1c: deterministic reduce (corr1T: 128 slices, xsum: 128, actsum: 512).
// ---------------------------------------------------------------------------
__global__ __launch_bounds__(256) void k_red1(
    const float* __restrict__ c1p, const float* __restrict__ xsp,
    const float* __restrict__ asp,
    float* __restrict__ corr1T, float* __restrict__ xsum,
    float* __restrict__ actsum) {
  const int e = blockIdx.x * 256 + threadIdx.x;  // < 65536
  float s = 0.f;
#pragma unroll 8
  for (int c = 0; c < NC1; ++c) s += c1p[(size_t)c * (IND * HID) + e];
  corr1T[e] = s;
  if (e < IND) {
    float t = 0.f;
#pragma unroll 8
    for (int c = 0; c < NC1; ++c) t += xsp[(size_t)c * IND + e];
    xsum[e] = t;
  }
  if (e < HID) {
    float t = 0.f;
#pragma unroll 8
    for (int c = 0; c < NSA; ++c) t += asp[(size_t)c * HID + e];
    actsum[e] = t;
  }
}

// ---------------------------------------------------------------------------
// K3: forward layer 2 + privatized corr2/outsum partials (fp32, r13-proven).
// grid = 2 o-tiles x 256 chunks(64 b) = 512 blocks (2 blk/CU).
// ---------------------------------------------------------------------------
__global__ __launch_bounds__(256, 2) void k_fwd2p(
    const float* __restrict__ act, const float* __restrict__ w2,
    float* __restrict__ out, float* __restrict__ corr2_part,
    float* __restrict__ outsum_part) {
  const int tid = threadIdx.x;
  const int o = (blockIdx.x & 1) * 256 + tid;
  const int chunk = blockIdx.x >> 1;
  const int b0 = chunk * 64;

  __shared__ float act_s[64][HID];
  {
    const float4* ag = (const float4*)(act + (size_t)b0 * HID);
    float4* as = (float4*)(&act_s[0][0]);
#pragma unroll
    for (int q = 0; q < 2; ++q) as[tid + 256 * q] = ag[tid + 256 * q];
  }

  const float4* w2p = (const float4*)(w2 + (size_t)o * HID);
  float4 w0 = w2p[0], w1r = w2p[1], w2r_ = w2p[2], w3 = w2p[3];
  float4 w4 = w2p[4], w5 = w2p[5], w6 = w2p[6], w7 = w2p[7];

  float4 s0{0,0,0,0}, s1{0,0,0,0}, s2{0,0,0,0}, s3{0,0,0,0};
  float4 s4{0,0,0,0}, s5{0,0,0,0}, s6{0,0,0,0}, s7{0,0,0,0};
  float osum = 0.f;

  __syncthreads();
  for (int b = 0; b < 64; ++b) {
    const float4* ar = (const float4*)(&act_s[b][0]);
    float4 a0 = ar[0], a1 = ar[1], a2 = ar[2], a3 = ar[3];
    float4 a4 = ar[4], a5 = ar[5], a6 = ar[6], a7 = ar[7];
    float z = 0.f;
    DOT4(z, a0, w0); DOT4(z, a1, w1r); DOT4(z, a2, w2r_); DOT4(z, a3, w3);
    DOT4(z, a4, w4); DOT4(z, a5, w5);  DOT4(z, a6, w6);   DOT4(z, a7, w7);
    float ov = 1.0f / (1.0f + __expf(-z)) - 0.4f;
    out[(size_t)(b0 + b) * OUTD + o] = ov;
    osum += ov;
    UPD4(s0, a0, ov); UPD4(s1, a1, ov); UPD4(s2, a2, ov); UPD4(s3, a3, ov);
    UPD4(s4, a4, ov); UPD4(s5, a5, ov); UPD4(s6, a6, ov); UPD4(s7, a7, ov);
  }

  float* c = corr2_part + (size_t)chunk * (HID * OUTD) + o;
  c[0 * OUTD]  = s0.x; c[1 * OUTD]  = s0.y; c[2 * OUTD]  = s0.z; c[3 * OUTD]  = s0.w;
  c[4 * OUTD]  = s1.x; c[5 * OUTD]  = s1.y; c[6 * OUTD]  = s1.z; c[7 * OUTD]  = s1.w;
  c[8 * OUTD]  = s2.x; c[9 * OUTD]  = s2.y; c[10 * OUTD] = s2.z; c[11 * OUTD] = s2.w;
  c[12 * OUTD] = s3.x; c[13 * OUTD] = s3.y; c[14 * OUTD] = s3.z; c[15 * OUTD] = s3.w;
  c[16 * OUTD] = s4.x; c[17 * OUTD] = s4.y; c[18 * OUTD] = s4.z; c[19 * OUTD] = s4.w;
  c[20 * OUTD] = s5.x; c[21 * OUTD] = s5.y; c[22 * OUTD] = s5.z; c[23 * OUTD] = s5.w;
  c[24 * OUTD] = s6.x; c[25 * OUTD] = s6.y; c[26 * OUTD] = s6.z; c[27 * OUTD] = s6.w;
  c[28 * OUTD] = s7.x; c[29 * OUTD] = s7.y; c[30 * OUTD] = s7.z; c[31 * OUTD] = s7.w;
  outsum_part[(size_t)chunk * OUTD + o] = osum;
}

// ---------------------------------------------------------------------------
// K3b: deterministic reduce of corr2/outsum partials (256 slices).
// ---------------------------------------------------------------------------
__global__ __launch_bounds__(256) void k_red2(
    const float* __restrict__ corr2_part, const float* __restrict__ outsum_part,
    float* __restrict__ corr2, float* __restrict__ outsum) {
  const int e = blockIdx.x * 256 + threadIdx.x;  // < 16384
  float s = 0.f;
#pragma unroll 8
  for (int c = 0; c < NC2; ++c) s += corr2_part[(size_t)c * (HID * OUTD) + e];
  corr2[e] = s;
  if (e < OUTD) {
    float t = 0.f;
#pragma unroll 8
    for (int c = 0; c < NC2; ++c) t += outsum_part[(size_t)c * OUTD + e];
    outsum[e] = t;
  }
}

// ---------------------------------------------------------------------------
// K4: w1_new[h,i] = (w1[h,i] + dw1T[i,h]) / ||row h||_2 ; corr1T[h][i].
// ---------------------------------------------------------------------------
__global__ __launch_bounds__(256) void k_w1(
    const float* __restrict__ w1, const float* __restrict__ heb,
    const float* __restrict__ corr1T, const float* __restrict__ xsum,
    const float* __restrict__ actsum, float* __restrict__ w1out) {
  const int h = blockIdx.x;
  const int tid = threadIdx.x;
  const float ash = actsum[h];
  const float4* heb4 = (const float4*)heb;

  float val[8];
  float ss = 0.f;
#pragma unroll
  for (int r = 0; r < 8; ++r) {
    const int i = tid + 256 * r;
    float4 c = heb4[(size_t)i * HID + h];
    float v = w1[(size_t)h * IND + i] + 16384.0f * c.w +
              c.x * corr1T[(size_t)h * IND + i] + c.y * xsum[i] + c.z * ash;
    val[r] = v;
    ss += v * v;
  }

  __shared__ float red[256];
  red[tid] = ss;
  __syncthreads();
  for (int s = 128; s > 0; s >>= 1) {
    if (tid < s) red[tid] += red[tid + s];
    __syncthreads();
  }
  const float inv = 1.0f / sqrtf(red[0]);
#pragma unroll
  for (int r = 0; r < 8; ++r) {
    const int i = tid + 256 * r;
    w1out[(size_t)h * IND + i] = val[r] * inv;
  }
}

// ---------------------------------------------------------------------------
// K5: w2_new[o,h] = (w2[o,h] + dw2T[h,o]) / ||row o||_2
// ---------------------------------------------------------------------------
__global__ __launch_bounds__(256) void k_w2(
    const float* __restrict__ w2, const float* __restrict__ heb,
    const float* __restrict__ corr2, const float* __restrict__ actsum,
    const float* __restrict__ outsum, float* __restrict__ w2out) {
  const int o = blockIdx.x * 256 + threadIdx.x;
  const float oso = outsum[o];
  const float4* heb4 = (const float4*)heb;

  float val[HID];
  float ss = 0.f;
#pragma unroll
  for (int h = 0; h < HID; ++h) {
    float4 c = heb4[(size_t)(HID * IND) + (size_t)h * OUTD + o];
    float v = w2[(size_t)o * HID + h] + 16384.0f * c.w +
              c.x * corr2[(size_t)h * OUTD + o] + c.y * actsum[h] + c.z * oso;
    val[h] = v;
    ss += v * v;
  }
  const float inv = 1.0f / sqrtf(ss);
#pragma unroll
  for (int h = 0; h < HID; ++h) w2out[(size_t)o * HID + h] = val[h] * inv;
}

// ---------------------------------------------------------------------------
extern "C" void kernel_launch(void* const* d_in, const int* in_sizes, int n_in,
                              void* d_out, int out_size, void* d_ws,
                              size_t ws_size, hipStream_t stream) {
  const float* x   = (const float*)d_in[0];   // [16384, 2048]
  const float* w1  = (const float*)d_in[1];   // [32, 2048]
  const float* w2  = (const float*)d_in[2];   // [512, 32]
  const float* heb = (const float*)d_in[3];   // [81920, 4]

  float* out = (float*)d_out;                 // [16384, 512]
  float* w1o = out + (size_t)BATCH * OUTD;    // [32, 2048]
  float* w2o = w1o + (size_t)HID * IND;       // [512, 32]

  float* ws = (float*)d_ws;                   // ws ~537 MB; layout ~56 MB
  float* act           = ws;                                     // 524288
  unsigned short* actT = (unsigned short*)(ws + (size_t)BATCH * HID);  // 524288 bf16
  float* corr1T        = ws + (size_t)BATCH * HID + BATCH * HID / 2;   // [h][i]
  float* corr2         = corr1T + (size_t)IND * HID;             // 16384
  float* xsum          = corr2 + (size_t)HID * OUTD;             // 2048
  float* actsum        = xsum + IND;                             // 32
  float* outsum        = actsum + HID;                           // 512
  float* corr1T_part   = outsum + OUTD;                          // 128*65536
  float* xsum_part     = corr1T_part + (size_t)NC1 * IND * HID;  // 128*2048
  float* actsum_part   = xsum_part + (size_t)NC1 * IND;          // 512*32
  float* corr2_part    = actsum_part + (size_t)NSA * HID;        // 256*16384
  float* outsum_part   = corr2_part + (size_t)NC2 * HID * OUTD;  // 256*512

  k_act  <<<512, 256, 0, stream>>>(x, w1, act, actT, actsum_part);
  k_corr1<<<512, 512, 0, stream>>>(x, actT, corr1T_part, xsum_part);
  k_red1 <<<256, 256, 0, stream>>>(corr1T_part, xsum_part, actsum_part,
                                   corr1T, xsum, actsum);
  k_fwd2p<<<512, 256, 0, stream>>>(act, w2, out, corr2_part, outsum_part);
  k_red2 <<<64, 256, 0, stream>>>(corr2_part, outsum_part, corr2, outsum);
  k_w1   <<<32, 256, 0, stream>>>(w1, heb, corr1T, xsum, actsum, w1o);
  k_w2   <<<2, 256, 0, stream>>>(w2, heb, corr2, actsum, outsum, w2o);
}

// Round 17
// 160.224 us; speedup vs baseline: 1.0065x; 1.0065x over previous
//
#include <hip/hip_runtime.h>
#include <math.h>

// Problem constants
constexpr int BATCH = 16384;
constexpr int IND   = 2048;   // INPUT
constexpr int HID   = 32;     // HIDDEN
constexpr int OUTD  = 512;    // OUTPUT

constexpr int NC1 = 256;      // corr1/xsum partial slices (b-chunks of 64)
constexpr int NSA = 64;       // actsum partial slices (k_actc blocks)
constexpr int NC2 = 256;      // corr2 b-chunks (64 b each)

constexpr int SA  = 136;      // ushort row stride, k_act tiles (128 k + pad)
constexpr int SXT = 72;       // ushort row stride, k_corr1 xT tile (64 b + pad)
constexpr int SAT = 72;       // ushort row stride, k_corr1 actT tile

typedef __attribute__((ext_vector_type(8))) short bf16x8;
typedef __attribute__((ext_vector_type(4))) float f32x4;

__device__ __forceinline__ unsigned short f2bf(float f) {
  unsigned u = __float_as_uint(f);
  u += 0x7FFFu + ((u >> 16) & 1u);          // round-to-nearest-even
  return (unsigned short)(u >> 16);
}
__device__ __forceinline__ float bf2f(unsigned short h) {
  return __uint_as_float(((unsigned)h) << 16);
}
__device__ __forceinline__ void split2(float f, unsigned short& hi,
                                       unsigned short& lo) {
  hi = f2bf(f);
  lo = f2bf(f - bf2f(hi));
}
// G4 XOR swizzle: spread fixed-column b128 reads across banks (8-ushort granule)
__device__ __forceinline__ int swzA(int row, int col) {
  return row * SA + (col ^ (((row >> 3) & 7) * 8));
}

#define UPD4(C, A, S)                 \
  (C).x = fmaf((S), (A).x, (C).x);    \
  (C).y = fmaf((S), (A).y, (C).y);    \
  (C).z = fmaf((S), (A).z, (C).z);    \
  (C).w = fmaf((S), (A).w, (C).w);

#define DOT4(Z, A, W)                 \
  (Z) = fmaf((A).x, (W).x, (Z));      \
  (Z) = fmaf((A).y, (W).y, (Z));      \
  (Z) = fmaf((A).z, (W).z, (Z));      \
  (Z) = fmaf((A).w, (W).w, (Z));

// ---------------------------------------------------------------------------
// K1a: act partials = x @ w1T (no relu yet), split-bf16 MFMA (r14-verified
// math). K-split x2 for occupancy: grid = 1024 = (bt 0..511 row-tiles of 32)
// x (kq 0..1 k-halves of 1024); launch_bounds(256,4) -> 4 blk/CU, 16 waves.
// r16's grid 512 = 2 blk/CU was grid-capped. All tiles G4-XOR-swizzled
// (r14/r15 residual 3.7M conflicts were the stride==4-dw-mod-32 pattern).
// ---------------------------------------------------------------------------
__global__ __launch_bounds__(256, 4) void k_act(
    const float* __restrict__ x, const float* __restrict__ w1,
    float* __restrict__ act_part) {
  const int tid = threadIdx.x;
  const int kq = blockIdx.x & 1;
  const int bt = blockIdx.x >> 1;          // 0..511
  const int b0 = bt * 32;
  const int kbase = kq * 1024;
  const int lane = tid & 63;
  const int wv = tid >> 6;                 // 0..3
  const int arow = lane & 15;
  const int m4 = lane >> 4;                // 0..3
  const int ksub = m4 * 8;
  const int rt = wv & 1;                   // row-tile (16 rows)
  const int ht = wv >> 1;                  // h-tile

  __shared__ __align__(16) unsigned short XH[32 * SA];
  __shared__ __align__(16) unsigned short XL[32 * SA];
  __shared__ __align__(16) unsigned short WH[32 * SA];
  __shared__ __align__(16) unsigned short WL[32 * SA];

  const int rp = tid >> 4;                 // 0..15 -> rows 2rp, 2rp+1
  const int kg = (tid & 15) * 8;

  float4 px0a, px0b, px1a, px1b, pw0a, pw0b, pw1a, pw1b;

#define LOADA(K0)                                                          \
  {                                                                        \
    const float* xr0 = x + (size_t)(b0 + 2 * rp) * IND + kbase + (K0) + kg;\
    const float* xr1 = xr0 + IND;                                          \
    px0a = *(const float4*)(xr0);                                          \
    px0b = *(const float4*)(xr0 + 4);                                      \
    px1a = *(const float4*)(xr1);                                          \
    px1b = *(const float4*)(xr1 + 4);                                      \
    const float* wr0 = w1 + (size_t)(2 * rp) * IND + kbase + (K0) + kg;    \
    const float* wr1 = wr0 + IND;                                          \
    pw0a = *(const float4*)(wr0);                                          \
    pw0b = *(const float4*)(wr0 + 4);                                      \
    pw1a = *(const float4*)(wr1);                                          \
    pw1b = *(const float4*)(wr1 + 4);                                      \
  }

#define PUT4(DSTH, DSTL, ROW, COL, V)                                \
  {                                                                  \
    ushort4 h_, l_;                                                  \
    split2((V).x, h_.x, l_.x); split2((V).y, h_.y, l_.y);            \
    split2((V).z, h_.z, l_.z); split2((V).w, h_.w, l_.w);            \
    *(ushort4*)(&(DSTH)[swzA((ROW), (COL))]) = h_;                   \
    *(ushort4*)(&(DSTL)[swzA((ROW), (COL))]) = l_;                   \
  }

#define STOREA                                                       \
  {                                                                  \
    PUT4(XH, XL, 2 * rp, kg, px0a);                                  \
    PUT4(XH, XL, 2 * rp, kg + 4, px0b);                              \
    PUT4(XH, XL, 2 * rp + 1, kg, px1a);                              \
    PUT4(XH, XL, 2 * rp + 1, kg + 4, px1b);                          \
    PUT4(WH, WL, 2 * rp, kg, pw0a);                                  \
    PUT4(WH, WL, 2 * rp, kg + 4, pw0b);                              \
    PUT4(WH, WL, 2 * rp + 1, kg, pw1a);                              \
    PUT4(WH, WL, 2 * rp + 1, kg + 4, pw1b);                          \
  }

  f32x4 accA = {0.f, 0.f, 0.f, 0.f};
  LOADA(0);

  for (int kc = 0; kc < 8; ++kc) {
    __syncthreads();                       // prev chunk's readers done
    STOREA;
    __syncthreads();                       // tiles visible
    if (kc < 7) LOADA((kc + 1) * 128);     // issue next loads EARLY
    const int xrow = rt * 16 + arow;
    const int wrow = ht * 16 + arow;
#pragma unroll
    for (int ks = 0; ks < 4; ++ks) {
      const int kk = ks * 32 + ksub;
      bf16x8 ah = *(const bf16x8*)(&XH[swzA(xrow, kk)]);
      bf16x8 al = *(const bf16x8*)(&XL[swzA(xrow, kk)]);
      bf16x8 bh = *(const bf16x8*)(&WH[swzA(wrow, kk)]);
      bf16x8 bl_ = *(const bf16x8*)(&WL[swzA(wrow, kk)]);
      accA = __builtin_amdgcn_mfma_f32_16x16x32_bf16(ah, bh, accA, 0, 0, 0);
      accA = __builtin_amdgcn_mfma_f32_16x16x32_bf16(ah, bl_, accA, 0, 0, 0);
      accA = __builtin_amdgcn_mfma_f32_16x16x32_bf16(al, bh, accA, 0, 0, 0);
    }
  }

  // C layout: col=lane&15 (h in tile), row=m4*4+r (b in tile)  [m89-verified]
  const int bl = rt * 16 + (m4 << 2);
  const int h = ht * 16 + arow;
  float* p = act_part + (size_t)kq * (BATCH * HID);
#pragma unroll
  for (int r = 0; r < 4; ++r)
    p[(size_t)(b0 + bl + r) * HID + h] = accA[r];
}

// ---------------------------------------------------------------------------
// K1b: combine 2 K-half partials -> relu -> act fp32 + actT bf16 [h][b] +
// actsum partials. grid = 64 x 256 (256 b-rows per block).
// ---------------------------------------------------------------------------
__global__ __launch_bounds__(256) void k_actc(
    const float* __restrict__ act_part, float* __restrict__ act,
    unsigned short* __restrict__ actT, float* __restrict__ actsum_part) {
  const int tid = threadIdx.x;
  const int blk = blockIdx.x;              // 0..63
  const int b0 = blk * 256;

  __shared__ unsigned short asT[32][264];
  __shared__ float red[256][4];

  const float4* p0 = (const float4*)act_part;
  const float4* p1 = p0 + (size_t)BATCH * HID / 4;
  float4* act4 = (float4*)act;

  const int hq = tid & 7;                  // fixed per thread
  float4 s{0.f, 0.f, 0.f, 0.f};
#pragma unroll
  for (int r = 0; r < 8; ++r) {
    const int e4 = r * 256 + tid;          // [256 b][8 hq]
    const int b = e4 >> 3;
    const size_t g = (size_t)(b0 + b) * 8 + hq;
    float4 a = p0[g];
    float4 c = p1[g];
    a.x = fmaxf(a.x + c.x, 0.f);  a.y = fmaxf(a.y + c.y, 0.f);
    a.z = fmaxf(a.z + c.z, 0.f);  a.w = fmaxf(a.w + c.w, 0.f);
    act4[g] = a;
    asT[hq * 4 + 0][b] = f2bf(a.x);
    asT[hq * 4 + 1][b] = f2bf(a.y);
    asT[hq * 4 + 2][b] = f2bf(a.z);
    asT[hq * 4 + 3][b] = f2bf(a.w);
    s.x += a.x; s.y += a.y; s.z += a.z; s.w += a.w;
  }
  red[tid][0] = s.x; red[tid][1] = s.y;
  red[tid][2] = s.z; red[tid][3] = s.w;
  __syncthreads();

#pragma unroll
  for (int r = 0; r < 4; ++r) {
    const int slot = r * 256 + tid;        // 1024 segments of 8 b
    const int hrow = slot >> 5;
    const int bseg = (slot & 31) * 8;
    bf16x8 v = *(const bf16x8*)(&asT[hrow][bseg]);
    *(bf16x8*)(&actT[(size_t)hrow * BATCH + b0 + bseg]) = v;
  }
  if (tid < 32) {
    const int q = tid >> 2, j = tid & 3;   // h = q*4 + j
    float t = 0.f;
#pragma unroll
    for (int sx = 0; sx < 32; ++sx) t += red[q + 8 * sx][j];
    actsum_part[blk * HID + tid] = t;
  }
}

// ---------------------------------------------------------------------------
// K1c: corr1T_part[bc][j][i] = sum_{b in 64-chunk} x[b,i]*act[b,j]; xsum via
// ones-tile B-fragment. grid = 1024 = (bc 0..255 b-chunks of 64) x (iq 0..3
// i-quadrants of 512). 512 thr, launch_bounds(512,4), 25KB LDS -> 2 blk/CU
// = 32 waves = FULL occupancy (r16 was 2 blk @ 16 waves). x^T XOR-swizzled
// (phys_b = b ^ ((i>>3)&7)*8, r14-proven); actT tile swizzled likewise.
// ---------------------------------------------------------------------------
__global__ __launch_bounds__(512, 4) void k_corr1(
    const float* __restrict__ x, const unsigned short* __restrict__ actT,
    float* __restrict__ corr1T_part, float* __restrict__ xsum_part) {
  const int tid = threadIdx.x;
  const int bc = blockIdx.x >> 2;          // 0..255
  const int iq = blockIdx.x & 3;           // 0..3
  const int b0 = bc * 64;
  const int ibase = iq * 512;
  const int lane = tid & 63;
  const int wv = tid >> 6;                 // 0..7
  const int arow = lane & 15;
  const int m4 = lane >> 4;
  const int ksub = m4 * 8;
  const int it = wv * 16;                  // wave's i-tile base in chunk

  __shared__ __align__(16) unsigned short XT[128 * SXT];
  __shared__ __align__(16) unsigned short AT[48 * SAT];

  // ones rows 32..47 (xsum tile; pads harmlessly ones too)
  for (int e = tid; e < 16 * SAT; e += 512)
    AT[32 * SAT + e] = (unsigned short)0x3F80;
  // stage actT tile [32 h][64 b], swizzled
  if (tid < 256) {
    const int hrow = tid >> 3;             // 0..31
    const int boff = (tid & 7) * 8;        // 0..56
    bf16x8 v = *(const bf16x8*)(&actT[(size_t)hrow * BATCH + b0 + boff]);
    *(bf16x8*)(&AT[hrow * SAT + (boff ^ (((hrow >> 3) & 7) * 8))]) = v;
  }

  const int ig = tid & 15;                 // i-group (8 i each)
  const int bq = tid >> 4;                 // 0..31 -> b rows 2bq, 2bq+1

  float4 xa, xb, ya, yb;

#define LOADC(IC)                                                     \
  {                                                                   \
    const int icol = ibase + (IC) * 128 + ig * 8;                     \
    const float* r0 = x + (size_t)(b0 + 2 * bq) * IND + icol;         \
    const float* r1 = r0 + IND;                                       \
    xa = *(const float4*)(r0); xb = *(const float4*)(r0 + 4);         \
    ya = *(const float4*)(r1); yb = *(const float4*)(r1 + 4);         \
  }

#define STC                                                                \
  {                                                                        \
    const int qb = (2 * bq) ^ ((ig & 7) * 8);                              \
    unsigned short* basew = &XT[(size_t)(ig * 8) * SXT + qb];              \
    ushort2 p;                                                             \
    p.x = f2bf(xa.x); p.y = f2bf(ya.x); *(ushort2*)(basew + 0 * SXT) = p;  \
    p.x = f2bf(xa.y); p.y = f2bf(ya.y); *(ushort2*)(basew + 1 * SXT) = p;  \
    p.x = f2bf(xa.z); p.y = f2bf(ya.z); *(ushort2*)(basew + 2 * SXT) = p;  \
    p.x = f2bf(xa.w); p.y = f2bf(ya.w); *(ushort2*)(basew + 3 * SXT) = p;  \
    p.x = f2bf(xb.x); p.y = f2bf(yb.x); *(ushort2*)(basew + 4 * SXT) = p;  \
    p.x = f2bf(xb.y); p.y = f2bf(yb.y); *(ushort2*)(basew + 5 * SXT) = p;  \
    p.x = f2bf(xb.z); p.y = f2bf(yb.z); *(ushort2*)(basew + 6 * SXT) = p;  \
    p.x = f2bf(xb.w); p.y = f2bf(yb.w); *(ushort2*)(basew + 7 * SXT) = p;  \
  }

  const int swzr = (((it + arow) >> 3) & 7) * 8;
  const int swze0 = ((arow >> 3) & 7) * 8;
  const int swze1 = (((16 + arow) >> 3) & 7) * 8;

  LOADC(0);
  for (int ic = 0; ic < 4; ++ic) {
    __syncthreads();                       // prev readers done (+AT/ones w0)
    STC;
    __syncthreads();
    if (ic < 3) LOADC(ic + 1);             // issue next loads EARLY

    f32x4 c00 = {0.f, 0.f, 0.f, 0.f};
    f32x4 c01 = {0.f, 0.f, 0.f, 0.f};
    f32x4 c02 = {0.f, 0.f, 0.f, 0.f};
#pragma unroll
    for (int bs = 0; bs < 2; ++bs) {
      const int bb = bs * 32 + ksub;
      bf16x8 a = *(const bf16x8*)(&XT[(it + arow) * SXT + (bb ^ swzr)]);
      bf16x8 e0 = *(const bf16x8*)(&AT[arow * SAT + (bb ^ swze0)]);
      bf16x8 e1 = *(const bf16x8*)(&AT[(16 + arow) * SAT + (bb ^ swze1)]);
      bf16x8 e2 = *(const bf16x8*)(&AT[(32 + arow) * SAT + bb]);
      c00 = __builtin_amdgcn_mfma_f32_16x16x32_bf16(a, e0, c00, 0, 0, 0);
      c01 = __builtin_amdgcn_mfma_f32_16x16x32_bf16(a, e1, c01, 0, 0, 0);
      c02 = __builtin_amdgcn_mfma_f32_16x16x32_bf16(a, e2, c02, 0, 0, 0);
    }
    float* basep = corr1T_part + (size_t)bc * (IND * HID);
    const int gi = ibase + ic * 128 + it + (m4 << 2);
    *(f32x4*)(basep + (size_t)arow * IND + gi) = c00;
    *(f32x4*)(basep + (size_t)(16 + arow) * IND + gi) = c01;
    if (arow == 0)
      *(f32x4*)(xsum_part + (size_t)bc * IND + gi) = c02;
  }
}

// ---------------------------------------------------------------------------
// K1d: deterministic reduce (corr1T/xsum: 256 slices, actsum: 64).
// ---------------------------------------------------------------------------
__global__ __launch_bounds__(256) void k_red1(
    const float* __restrict__ c1p, const float* __restrict__ xsp,
    const float* __restrict__ asp,
    float* __restrict__ corr1T, float* __restrict__ xsum,
    float* __restrict__ actsum) {
  const int e = blockIdx.x * 256 + threadIdx.x;  // < 65536
  float s = 0.f;
#pragma unroll 8
  for (int c = 0; c < NC1; ++c) s += c1p[(size_t)c * (IND * HID) + e];
  corr1T[e] = s;
  if (e < IND) {
    float t = 0.f;
#pragma unroll 8
    for (int c = 0; c < NC1; ++c) t += xsp[(size_t)c * IND + e];
    xsum[e] = t;
  }
  if (e < HID) {
    float t = 0.f;
#pragma unroll 8
    for (int c = 0; c < NSA; ++c) t += asp[(size_t)c * HID + e];
    actsum[e] = t;
  }
}

// ---------------------------------------------------------------------------
// K3: forward layer 2 + privatized corr2/outsum partials (fp32, r13-proven).
// grid = 2 o-tiles x 256 chunks(64 b) = 512 blocks (2 blk/CU).
// ---------------------------------------------------------------------------
__global__ __launch_bounds__(256, 2) void k_fwd2p(
    const float* __restrict__ act, const float* __restrict__ w2,
    float* __restrict__ out, float* __restrict__ corr2_part,
    float* __restrict__ outsum_part) {
  const int tid = threadIdx.x;
  const int o = (blockIdx.x & 1) * 256 + tid;
  const int chunk = blockIdx.x >> 1;
  const int b0 = chunk * 64;

  __shared__ float act_s[64][HID];
  {
    const float4* ag = (const float4*)(act + (size_t)b0 * HID);
    float4* as = (float4*)(&act_s[0][0]);
#pragma unroll
    for (int q = 0; q < 2; ++q) as[tid + 256 * q] = ag[tid + 256 * q];
  }

  const float4* w2p = (const float4*)(w2 + (size_t)o * HID);
  float4 w0 = w2p[0], w1r = w2p[1], w2r_ = w2p[2], w3 = w2p[3];
  float4 w4 = w2p[4], w5 = w2p[5], w6 = w2p[6], w7 = w2p[7];

  float4 s0{0,0,0,0}, s1{0,0,0,0}, s2{0,0,0,0}, s3{0,0,0,0};
  float4 s4{0,0,0,0}, s5{0,0,0,0}, s6{0,0,0,0}, s7{0,0,0,0};
  float osum = 0.f;

  __syncthreads();
  for (int b = 0; b < 64; ++b) {
    const float4* ar = (const float4*)(&act_s[b][0]);
    float4 a0 = ar[0], a1 = ar[1], a2 = ar[2], a3 = ar[3];
    float4 a4 = ar[4], a5 = ar[5], a6 = ar[6], a7 = ar[7];
    float z = 0.f;
    DOT4(z, a0, w0); DOT4(z, a1, w1r); DOT4(z, a2, w2r_); DOT4(z, a3, w3);
    DOT4(z, a4, w4); DOT4(z, a5, w5);  DOT4(z, a6, w6);   DOT4(z, a7, w7);
    float ov = 1.0f / (1.0f + __expf(-z)) - 0.4f;
    out[(size_t)(b0 + b) * OUTD + o] = ov;
    osum += ov;
    UPD4(s0, a0, ov); UPD4(s1, a1, ov); UPD4(s2, a2, ov); UPD4(s3, a3, ov);
    UPD4(s4, a4, ov); UPD4(s5, a5, ov); UPD4(s6, a6, ov); UPD4(s7, a7, ov);
  }

  float* c = corr2_part + (size_t)chunk * (HID * OUTD) + o;
  c[0 * OUTD]  = s0.x; c[1 * OUTD]  = s0.y; c[2 * OUTD]  = s0.z; c[3 * OUTD]  = s0.w;
  c[4 * OUTD]  = s1.x; c[5 * OUTD]  = s1.y; c[6 * OUTD]  = s1.z; c[7 * OUTD]  = s1.w;
  c[8 * OUTD]  = s2.x; c[9 * OUTD]  = s2.y; c[10 * OUTD] = s2.z; c[11 * OUTD] = s2.w;
  c[12 * OUTD] = s3.x; c[13 * OUTD] = s3.y; c[14 * OUTD] = s3.z; c[15 * OUTD] = s3.w;
  c[16 * OUTD] = s4.x; c[17 * OUTD] = s4.y; c[18 * OUTD] = s4.z; c[19 * OUTD] = s4.w;
  c[20 * OUTD] = s5.x; c[21 * OUTD] = s5.y; c[22 * OUTD] = s5.z; c[23 * OUTD] = s5.w;
  c[24 * OUTD] = s6.x; c[25 * OUTD] = s6.y; c[26 * OUTD] = s6.z; c[27 * OUTD] = s6.w;
  c[28 * OUTD] = s7.x; c[29 * OUTD] = s7.y; c[30 * OUTD] = s7.z; c[31 * OUTD] = s7.w;
  outsum_part[(size_t)chunk * OUTD + o] = osum;
}

// ---------------------------------------------------------------------------
// K3b: deterministic reduce of corr2/outsum partials (256 slices).
// ---------------------------------------------------------------------------
__global__ __launch_bounds__(256) void k_red2(
    const float* __restrict__ corr2_part, const float* __restrict__ outsum_part,
    float* __restrict__ corr2, float* __restrict__ outsum) {
  const int e = blockIdx.x * 256 + threadIdx.x;  // < 16384
  float s = 0.f;
#pragma unroll 8
  for (int c = 0; c < NC2; ++c) s += corr2_part[(size_t)c * (HID * OUTD) + e];
  corr2[e] = s;
  if (e < OUTD) {
    float t = 0.f;
#pragma unroll 8
    for (int c = 0; c < NC2; ++c) t += outsum_part[(size_t)c * OUTD + e];
    outsum[e] = t;
  }
}

// ---------------------------------------------------------------------------
// K4: w1_new[h,i] = (w1[h,i] + dw1T[i,h]) / ||row h||_2 ; corr1T[h][i].
// ---------------------------------------------------------------------------
__global__ __launch_bounds__(256) void k_w1(
    const float* __restrict__ w1, const float* __restrict__ heb,
    const float* __restrict__ corr1T, const float* __restrict__ xsum,
    const float* __restrict__ actsum, float* __restrict__ w1out) {
  const int h = blockIdx.x;
  const int tid = threadIdx.x;
  const float ash = actsum[h];
  const float4* heb4 = (const float4*)heb;

  float val[8];
  float ss = 0.f;
#pragma unroll
  for (int r = 0; r < 8; ++r) {
    const int i = tid + 256 * r;
    float4 c = heb4[(size_t)i * HID + h];
    float v = w1[(size_t)h * IND + i] + 16384.0f * c.w +
              c.x * corr1T[(size_t)h * IND + i] + c.y * xsum[i] + c.z * ash;
    val[r] = v;
    ss += v * v;
  }

  __shared__ float red[256];
  red[tid] = ss;
  __syncthreads();
  for (int s = 128; s > 0; s >>= 1) {
    if (tid < s) red[tid] += red[tid + s];
    __syncthreads();
  }
  const float inv = 1.0f / sqrtf(red[0]);
#pragma unroll
  for (int r = 0; r < 8; ++r) {
    const int i = tid + 256 * r;
    w1out[(size_t)h * IND + i] = val[r] * inv;
  }
}

// ---------------------------------------------------------------------------
// K5: w2_new[o,h] = (w2[o,h] + dw2T[h,o]) / ||row o||_2
// ---------------------------------------------------------------------------
__global__ __launch_bounds__(256) void k_w2(
    const float* __restrict__ w2, const float* __restrict__ heb,
    const float* __restrict__ corr2, const float* __restrict__ actsum,
    const float* __restrict__ outsum, float* __restrict__ w2out) {
  const int o = blockIdx.x * 256 + threadIdx.x;
  const float oso = outsum[o];
  const float4* heb4 = (const float4*)heb;

  float val[HID];
  float ss = 0.f;
#pragma unroll
  for (int h = 0; h < HID; ++h) {
    float4 c = heb4[(size_t)(HID * IND) + (size_t)h * OUTD + o];
    float v = w2[(size_t)o * HID + h] + 16384.0f * c.w +
              c.x * corr2[(size_t)h * OUTD + o] + c.y * actsum[h] + c.z * oso;
    val[h] = v;
    ss += v * v;
  }
  const float inv = 1.0f / sqrtf(ss);
#pragma unroll
  for (int h = 0; h < HID; ++h) w2out[(size_t)o * HID + h] = val[h] * inv;
}

// ---------------------------------------------------------------------------
extern "C" void kernel_launch(void* const* d_in, const int* in_sizes, int n_in,
                              void* d_out, int out_size, void* d_ws,
                              size_t ws_size, hipStream_t stream) {
  const float* x   = (const float*)d_in[0];   // [16384, 2048]
  const float* w1  = (const float*)d_in[1];   // [32, 2048]
  const float* w2  = (const float*)d_in[2];   // [512, 32]
  const float* heb = (const float*)d_in[3];   // [81920, 4]

  float* out = (float*)d_out;                 // [16384, 512]
  float* w1o = out + (size_t)BATCH * OUTD;    // [32, 2048]
  float* w2o = w1o + (size_t)HID * IND;       // [512, 32]

  float* ws = (float*)d_ws;                   // ws ~537 MB; layout ~94 MB
  float* act           = ws;                                     // 524288
  unsigned short* actT = (unsigned short*)(ws + (size_t)BATCH * HID);  // 262144 f
  float* corr1T        = ws + (size_t)BATCH * HID + BATCH * HID / 2;   // [h][i]
  float* corr2         = corr1T + (size_t)IND * HID;             // 16384
  float* xsum          = corr2 + (size_t)HID * OUTD;             // 2048
  float* actsum        = xsum + IND;                             // 32
  float* outsum        = actsum + HID;                           // 512
  float* act_part      = outsum + OUTD;                          // 2*524288
  float* corr1T_part   = act_part + (size_t)2 * BATCH * HID;     // 256*65536
  float* xsum_part     = corr1T_part + (size_t)NC1 * IND * HID;  // 256*2048
  float* actsum_part   = xsum_part + (size_t)NC1 * IND;          // 64*32
  float* corr2_part    = actsum_part + (size_t)NSA * HID;        // 256*16384
  float* outsum_part   = corr2_part + (size_t)NC2 * HID * OUTD;  // 256*512

  k_act  <<<1024, 256, 0, stream>>>(x, w1, act_part);
  k_actc <<<64, 256, 0, stream>>>(act_part, act, actT, actsum_part);
  k_corr1<<<1024, 512, 0, stream>>>(x, actT, corr1T_part, xsum_part);
  k_red1 <<<256, 256, 0, stream>>>(corr1T_part, xsum_part, actsum_part,
                                   corr1T, xsum, actsum);
  k_fwd2p<<<512, 256, 0, stream>>>(act, w2, out, corr2_part, outsum_part);
  k_red2 <<<64, 256, 0, stream>>>(corr2_part, outsum_part, corr2, outsum);
  k_w1   <<<32, 256, 0, stream>>>(w1, heb, corr1T, xsum, actsum, w1o);
  k_w2   <<<2, 256, 0, stream>>>(w2, heb, corr2, actsum, outsum, w2o);
}

// Round 18
// 151.517 us; speedup vs baseline: 1.0643x; 1.0575x over previous
//
#include <hip/hip_runtime.h>
#include <math.h>

// Problem constants
constexpr int BATCH = 16384;
constexpr int IND   = 2048;   // INPUT
constexpr int HID   = 32;     // HIDDEN
constexpr int OUTD  = 512;    // OUTPUT

constexpr int NC1 = 256;      // corr1/xsum partial slices (b-chunks of 64)
constexpr int NSA = 64;       // actsum partial slices (k_actc blocks)
constexpr int NC2 = 256;      // corr2/outsum partial slices (b-chunks of 64)

constexpr int SA  = 136;      // ushort row stride, k_act tiles
constexpr int SXT = 72;       // ushort row stride, k_corr1 xT tile
constexpr int SAT = 72;       // ushort row stride, k_corr1 actT tile

typedef __attribute__((ext_vector_type(8))) short bf16x8;
typedef __attribute__((ext_vector_type(4))) float f32x4;

__device__ __forceinline__ unsigned short f2bf(float f) {
  unsigned u = __float_as_uint(f);
  u += 0x7FFFu + ((u >> 16) & 1u);          // round-to-nearest-even
  return (unsigned short)(u >> 16);
}
__device__ __forceinline__ float bf2f(unsigned short h) {
  return __uint_as_float(((unsigned)h) << 16);
}
__device__ __forceinline__ void split2(float f, unsigned short& hi,
                                       unsigned short& lo) {
  hi = f2bf(f);
  lo = f2bf(f - bf2f(hi));
}
__device__ __forceinline__ int swzA(int row, int col) {
  return row * SA + (col ^ (((row >> 3) & 7) * 8));
}

// ---------------------------------------------------------------------------
// K1a: act partials = x @ w1T (no relu), split-bf16 MFMA. r17-verbatim.
// grid = 1024 = (bt 0..511 x 32 rows) x (kq 0..1), (256,4).
// ---------------------------------------------------------------------------
__global__ __launch_bounds__(256, 4) void k_act(
    const float* __restrict__ x, const float* __restrict__ w1,
    float* __restrict__ act_part) {
  const int tid = threadIdx.x;
  const int kq = blockIdx.x & 1;
  const int bt = blockIdx.x >> 1;          // 0..511
  const int b0 = bt * 32;
  const int kbase = kq * 1024;
  const int lane = tid & 63;
  const int wv = tid >> 6;                 // 0..3
  const int arow = lane & 15;
  const int m4 = lane >> 4;                // 0..3
  const int ksub = m4 * 8;
  const int rt = wv & 1;
  const int ht = wv >> 1;

  __shared__ __align__(16) unsigned short XH[32 * SA];
  __shared__ __align__(16) unsigned short XL[32 * SA];
  __shared__ __align__(16) unsigned short WH[32 * SA];
  __shared__ __align__(16) unsigned short WL[32 * SA];

  const int rp = tid >> 4;
  const int kg = (tid & 15) * 8;

  float4 px0a, px0b, px1a, px1b, pw0a, pw0b, pw1a, pw1b;

#define LOADA(K0)                                                          \
  {                                                                        \
    const float* xr0 = x + (size_t)(b0 + 2 * rp) * IND + kbase + (K0) + kg;\
    const float* xr1 = xr0 + IND;                                          \
    px0a = *(const float4*)(xr0);                                          \
    px0b = *(const float4*)(xr0 + 4);                                      \
    px1a = *(const float4*)(xr1);                                          \
    px1b = *(const float4*)(xr1 + 4);                                      \
    const float* wr0 = w1 + (size_t)(2 * rp) * IND + kbase + (K0) + kg;    \
    const float* wr1 = wr0 + IND;                                          \
    pw0a = *(const float4*)(wr0);                                          \
    pw0b = *(const float4*)(wr0 + 4);                                      \
    pw1a = *(const float4*)(wr1);                                          \
    pw1b = *(const float4*)(wr1 + 4);                                      \
  }

#define PUT4(DSTH, DSTL, ROW, COL, V)                                \
  {                                                                  \
    ushort4 h_, l_;                                                  \
    split2((V).x, h_.x, l_.x); split2((V).y, h_.y, l_.y);            \
    split2((V).z, h_.z, l_.z); split2((V).w, h_.w, l_.w);            \
    *(ushort4*)(&(DSTH)[swzA((ROW), (COL))]) = h_;                   \
    *(ushort4*)(&(DSTL)[swzA((ROW), (COL))]) = l_;                   \
  }

#define STOREA                                                       \
  {                                                                  \
    PUT4(XH, XL, 2 * rp, kg, px0a);                                  \
    PUT4(XH, XL, 2 * rp, kg + 4, px0b);                              \
    PUT4(XH, XL, 2 * rp + 1, kg, px1a);                              \
    PUT4(XH, XL, 2 * rp + 1, kg + 4, px1b);                          \
    PUT4(WH, WL, 2 * rp, kg, pw0a);                                  \
    PUT4(WH, WL, 2 * rp, kg + 4, pw0b);                              \
    PUT4(WH, WL, 2 * rp + 1, kg, pw1a);                              \
    PUT4(WH, WL, 2 * rp + 1, kg + 4, pw1b);                          \
  }

  f32x4 accA = {0.f, 0.f, 0.f, 0.f};
  LOADA(0);

  for (int kc = 0; kc < 8; ++kc) {
    __syncthreads();
    STOREA;
    __syncthreads();
    if (kc < 7) LOADA((kc + 1) * 128);
    const int xrow = rt * 16 + arow;
    const int wrow = ht * 16 + arow;
#pragma unroll
    for (int ks = 0; ks < 4; ++ks) {
      const int kk = ks * 32 + ksub;
      bf16x8 ah = *(const bf16x8*)(&XH[swzA(xrow, kk)]);
      bf16x8 al = *(const bf16x8*)(&XL[swzA(xrow, kk)]);
      bf16x8 bh = *(const bf16x8*)(&WH[swzA(wrow, kk)]);
      bf16x8 bl_ = *(const bf16x8*)(&WL[swzA(wrow, kk)]);
      accA = __builtin_amdgcn_mfma_f32_16x16x32_bf16(ah, bh, accA, 0, 0, 0);
      accA = __builtin_amdgcn_mfma_f32_16x16x32_bf16(ah, bl_, accA, 0, 0, 0);
      accA = __builtin_amdgcn_mfma_f32_16x16x32_bf16(al, bh, accA, 0, 0, 0);
    }
  }

  const int bl = rt * 16 + (m4 << 2);
  const int h = ht * 16 + arow;
  float* p = act_part + (size_t)kq * (BATCH * HID);
#pragma unroll
  for (int r = 0; r < 4; ++r)
    p[(size_t)(b0 + bl + r) * HID + h] = accA[r];
}

// ---------------------------------------------------------------------------
// K1b: combine 2 K-half partials -> relu -> actH/actL bf16 [b][h] (split,
// feeds k_fwd2m's A operand) + actT bf16 [h][b] (feeds corr1 B / corr2 A) +
// actsum partials. fp32 act dropped (nothing reads it anymore).
// grid = 64 x 256 (256 b-rows per block).
// ---------------------------------------------------------------------------
__global__ __launch_bounds__(256) void k_actc(
    const float* __restrict__ act_part,
    unsigned short* __restrict__ actH, unsigned short* __restrict__ actL,
    unsigned short* __restrict__ actT, float* __restrict__ actsum_part) {
  const int tid = threadIdx.x;
  const int blk = blockIdx.x;              // 0..63
  const int b0 = blk * 256;

  __shared__ unsigned short asT[32][264];
  __shared__ float red[256][4];

  const float4* p0 = (const float4*)act_part;
  const float4* p1 = p0 + (size_t)BATCH * HID / 4;

  const int hq = tid & 7;
  float4 s{0.f, 0.f, 0.f, 0.f};
#pragma unroll
  for (int r = 0; r < 8; ++r) {
    const int e4 = r * 256 + tid;
    const int b = e4 >> 3;
    const size_t g = (size_t)(b0 + b) * 8 + hq;
    float4 a = p0[g];
    float4 c = p1[g];
    a.x = fmaxf(a.x + c.x, 0.f);  a.y = fmaxf(a.y + c.y, 0.f);
    a.z = fmaxf(a.z + c.z, 0.f);  a.w = fmaxf(a.w + c.w, 0.f);
    ushort4 hh, ll;
    split2(a.x, hh.x, ll.x); split2(a.y, hh.y, ll.y);
    split2(a.z, hh.z, ll.z); split2(a.w, hh.w, ll.w);
    *(ushort4*)(&actH[g * 4]) = hh;
    *(ushort4*)(&actL[g * 4]) = ll;
    asT[hq * 4 + 0][b] = hh.x;
    asT[hq * 4 + 1][b] = hh.y;
    asT[hq * 4 + 2][b] = hh.z;
    asT[hq * 4 + 3][b] = hh.w;
    s.x += a.x; s.y += a.y; s.z += a.z; s.w += a.w;
  }
  red[tid][0] = s.x; red[tid][1] = s.y;
  red[tid][2] = s.z; red[tid][3] = s.w;
  __syncthreads();

#pragma unroll
  for (int r = 0; r < 4; ++r) {
    const int slot = r * 256 + tid;
    const int hrow = slot >> 5;
    const int bseg = (slot & 31) * 8;
    bf16x8 v = *(const bf16x8*)(&asT[hrow][bseg]);
    *(bf16x8*)(&actT[(size_t)hrow * BATCH + b0 + bseg]) = v;
  }
  if (tid < 32) {
    const int q = tid >> 2, j = tid & 3;
    float t = 0.f;
#pragma unroll
    for (int sx = 0; sx < 32; ++sx) t += red[q + 8 * sx][j];
    actsum_part[blk * HID + tid] = t;
  }
}

// ---------------------------------------------------------------------------
// K1c: corr1T_part = x^T @ act (+ xsum via ones tile). r17-verbatim.
// grid = 1024 = (bc 0..255 x 64 b) x (iq 0..3), 512 thr, (512,4).
// ---------------------------------------------------------------------------
__global__ __launch_bounds__(512, 4) void k_corr1(
    const float* __restrict__ x, const unsigned short* __restrict__ actT,
    float* __restrict__ corr1T_part, float* __restrict__ xsum_part) {
  const int tid = threadIdx.x;
  const int bc = blockIdx.x >> 2;
  const int iq = blockIdx.x & 3;
  const int b0 = bc * 64;
  const int ibase = iq * 512;
  const int lane = tid & 63;
  const int wv = tid >> 6;
  const int arow = lane & 15;
  const int m4 = lane >> 4;
  const int ksub = m4 * 8;
  const int it = wv * 16;

  __shared__ __align__(16) unsigned short XT[128 * SXT];
  __shared__ __align__(16) unsigned short AT[48 * SAT];

  for (int e = tid; e < 16 * SAT; e += 512)
    AT[32 * SAT + e] = (unsigned short)0x3F80;
  if (tid < 256) {
    const int hrow = tid >> 3;
    const int boff = (tid & 7) * 8;
    bf16x8 v = *(const bf16x8*)(&actT[(size_t)hrow * BATCH + b0 + boff]);
    *(bf16x8*)(&AT[hrow * SAT + (boff ^ (((hrow >> 3) & 7) * 8))]) = v;
  }

  const int ig = tid & 15;
  const int bq = tid >> 4;

  float4 xa, xb, ya, yb;

#define LOADC(IC)                                                     \
  {                                                                   \
    const int icol = ibase + (IC) * 128 + ig * 8;                     \
    const float* r0 = x + (size_t)(b0 + 2 * bq) * IND + icol;         \
    const float* r1 = r0 + IND;                                       \
    xa = *(const float4*)(r0); xb = *(const float4*)(r0 + 4);         \
    ya = *(const float4*)(r1); yb = *(const float4*)(r1 + 4);         \
  }

#define STC                                                                \
  {                                                                        \
    const int qb = (2 * bq) ^ ((ig & 7) * 8);                              \
    unsigned short* basew = &XT[(size_t)(ig * 8) * SXT + qb];              \
    ushort2 p;                                                             \
    p.x = f2bf(xa.x); p.y = f2bf(ya.x); *(ushort2*)(basew + 0 * SXT) = p;  \
    p.x = f2bf(xa.y); p.y = f2bf(ya.y); *(ushort2*)(basew + 1 * SXT) = p;  \
    p.x = f2bf(xa.z); p.y = f2bf(ya.z); *(ushort2*)(basew + 2 * SXT) = p;  \
    p.x = f2bf(xa.w); p.y = f2bf(ya.w); *(ushort2*)(basew + 3 * SXT) = p;  \
    p.x = f2bf(xb.x); p.y = f2bf(yb.x); *(ushort2*)(basew + 4 * SXT) = p;  \
    p.x = f2bf(xb.y); p.y = f2bf(yb.y); *(ushort2*)(basew + 5 * SXT) = p;  \
    p.x = f2bf(xb.z); p.y = f2bf(yb.z); *(ushort2*)(basew + 6 * SXT) = p;  \
    p.x = f2bf(xb.w); p.y = f2bf(yb.w); *(ushort2*)(basew + 7 * SXT) = p;  \
  }

  const int swzr = (((it + arow) >> 3) & 7) * 8;
  const int swze0 = ((arow >> 3) & 7) * 8;
  const int swze1 = (((16 + arow) >> 3) & 7) * 8;

  LOADC(0);
  for (int ic = 0; ic < 4; ++ic) {
    __syncthreads();
    STC;
    __syncthreads();
    if (ic < 3) LOADC(ic + 1);

    f32x4 c00 = {0.f, 0.f, 0.f, 0.f};
    f32x4 c01 = {0.f, 0.f, 0.f, 0.f};
    f32x4 c02 = {0.f, 0.f, 0.f, 0.f};
#pragma unroll
    for (int bs = 0; bs < 2; ++bs) {
      const int bb = bs * 32 + ksub;
      bf16x8 a = *(const bf16x8*)(&XT[(it + arow) * SXT + (bb ^ swzr)]);
      bf16x8 e0 = *(const bf16x8*)(&AT[arow * SAT + (bb ^ swze0)]);
      bf16x8 e1 = *(const bf16x8*)(&AT[(16 + arow) * SAT + (bb ^ swze1)]);
      bf16x8 e2 = *(const bf16x8*)(&AT[(32 + arow) * SAT + bb]);
      c00 = __builtin_amdgcn_mfma_f32_16x16x32_bf16(a, e0, c00, 0, 0, 0);
      c01 = __builtin_amdgcn_mfma_f32_16x16x32_bf16(a, e1, c01, 0, 0, 0);
      c02 = __builtin_amdgcn_mfma_f32_16x16x32_bf16(a, e2, c02, 0, 0, 0);
    }
    float* basep = corr1T_part + (size_t)bc * (IND * HID);
    const int gi = ibase + ic * 128 + it + (m4 << 2);
    *(f32x4*)(basep + (size_t)arow * IND + gi) = c00;
    *(f32x4*)(basep + (size_t)(16 + arow) * IND + gi) = c01;
    if (arow == 0)
      *(f32x4*)(xsum_part + (size_t)bc * IND + gi) = c02;
  }
}

// ---------------------------------------------------------------------------
// K1d: deterministic reduce (corr1T/xsum: 256 slices, actsum: 64).
// ---------------------------------------------------------------------------
__global__ __launch_bounds__(256) void k_red1(
    const float* __restrict__ c1p, const float* __restrict__ xsp,
    const float* __restrict__ asp,
    float* __restrict__ corr1T, float* __restrict__ xsum,
    float* __restrict__ actsum) {
  const int e = blockIdx.x * 256 + threadIdx.x;
  float s = 0.f;
#pragma unroll 8
  for (int c = 0; c < NC1; ++c) s += c1p[(size_t)c * (IND * HID) + e];
  corr1T[e] = s;
  if (e < IND) {
    float t = 0.f;
#pragma unroll 8
    for (int c = 0; c < NC1; ++c) t += xsp[(size_t)c * IND + e];
    xsum[e] = t;
  }
  if (e < HID) {
    float t = 0.f;
#pragma unroll 8
    for (int c = 0; c < NSA; ++c) t += asp[(size_t)c * HID + e];
    actsum[e] = t;
  }
}

// ---------------------------------------------------------------------------
// K3: layer-2 MFMA. Forward: z = act @ w2T via split-bf16 (3 MFMA, K=32 =
// one frag); out = sigmoid(z)-0.4 on C-frags. corr2/outsum: MFMA over K=b
// (A = actT [h][b] hi + ones rows; B = out tile [o][b] bf16 in LDS).
// grid = 1024 = (bc 0..255 x 64 b) x (og 0..3 x 128 o); 256 thr, 56KB LDS.
// Replaces the fp32-VALU k_fwd2p (last non-MFMA GEMM in the pipeline).
// ---------------------------------------------------------------------------
__global__ __launch_bounds__(256, 2) void k_fwd2m(
    const unsigned short* __restrict__ actH,
    const unsigned short* __restrict__ actL,
    const unsigned short* __restrict__ actT, const float* __restrict__ w2,
    float* __restrict__ out, float* __restrict__ corr2_part,
    float* __restrict__ outsum_part) {
  const int tid = threadIdx.x;
  const int bc = blockIdx.x >> 2;          // 0..255
  const int og = blockIdx.x & 3;           // 0..3
  const int b0 = bc * 64;
  const int obase = og * 128;
  const int lane = tid & 63;
  const int wv = tid >> 6;                 // 0..3
  const int arow = lane & 15;
  const int m4 = lane >> 4;
  const int ksub = m4 * 8;

  __shared__ __align__(16) unsigned short W2H[128 * 40];
  __shared__ __align__(16) unsigned short W2L[128 * 40];
  __shared__ __align__(16) unsigned short AH[64 * 40];
  __shared__ __align__(16) unsigned short AL[64 * 40];
  __shared__ __align__(16) unsigned short AT[48 * 72];
  __shared__ __align__(16) unsigned short OT[128 * 72];

  {  // stage w2 hi/lo: thread = (o-row r2, h-half hh)
    const int r2 = tid >> 1, hh = (tid & 1) * 16;
    const float* wr = w2 + (size_t)(obase + r2) * HID + hh;
#pragma unroll
    for (int j = 0; j < 4; ++j) {
      float4 v = *(const float4*)(wr + 4 * j);
      ushort4 h_, l_;
      split2(v.x, h_.x, l_.x); split2(v.y, h_.y, l_.y);
      split2(v.z, h_.z, l_.z); split2(v.w, h_.w, l_.w);
      *(ushort4*)(&W2H[r2 * 40 + hh + 4 * j]) = h_;
      *(ushort4*)(&W2L[r2 * 40 + hh + 4 * j]) = l_;
    }
  }
  {  // stage act hi/lo [64 b][32 h]
    const int b = tid >> 2, q = (tid & 3) * 8;
    *(bf16x8*)(&AH[b * 40 + q]) =
        *(const bf16x8*)(&actH[(size_t)(b0 + b) * HID + q]);
    *(bf16x8*)(&AL[b * 40 + q]) =
        *(const bf16x8*)(&actL[(size_t)(b0 + b) * HID + q]);
  }
  {  // stage actT [32 h][64 b] + ones rows 32..47
    const int h = tid >> 3, seg = (tid & 7) * 8;
    *(bf16x8*)(&AT[h * 72 + seg]) =
        *(const bf16x8*)(&actT[(size_t)h * BATCH + b0 + seg]);
  }
  for (int e = tid; e < 16 * 72; e += 256)
    AT[32 * 72 + e] = (unsigned short)0x3F80;
  __syncthreads();

  // forward: wave = b-tile
  const int bt = wv;
  bf16x8 fah = *(const bf16x8*)(&AH[(bt * 16 + arow) * 40 + ksub]);
  bf16x8 fal = *(const bf16x8*)(&AL[(bt * 16 + arow) * 40 + ksub]);
#pragma unroll
  for (int ot = 0; ot < 8; ++ot) {
    bf16x8 wbh = *(const bf16x8*)(&W2H[(ot * 16 + arow) * 40 + ksub]);
    bf16x8 wbl = *(const bf16x8*)(&W2L[(ot * 16 + arow) * 40 + ksub]);
    f32x4 z = {0.f, 0.f, 0.f, 0.f};
    z = __builtin_amdgcn_mfma_f32_16x16x32_bf16(fah, wbh, z, 0, 0, 0);
    z = __builtin_amdgcn_mfma_f32_16x16x32_bf16(fah, wbl, z, 0, 0, 0);
    z = __builtin_amdgcn_mfma_f32_16x16x32_bf16(fal, wbh, z, 0, 0, 0);
    ushort4 po;
    {
      float ov0 = 1.0f / (1.0f + __expf(-z[0])) - 0.4f;
      float ov1 = 1.0f / (1.0f + __expf(-z[1])) - 0.4f;
      float ov2 = 1.0f / (1.0f + __expf(-z[2])) - 0.4f;
      float ov3 = 1.0f / (1.0f + __expf(-z[3])) - 0.4f;
      const size_t ob = (size_t)(b0 + bt * 16 + m4 * 4) * OUTD +
                        obase + ot * 16 + arow;
      out[ob + 0 * OUTD] = ov0;
      out[ob + 1 * OUTD] = ov1;
      out[ob + 2 * OUTD] = ov2;
      out[ob + 3 * OUTD] = ov3;
      po.x = f2bf(ov0); po.y = f2bf(ov1); po.z = f2bf(ov2); po.w = f2bf(ov3);
    }
    *(ushort4*)(&OT[(ot * 16 + arow) * 72 + bt * 16 + m4 * 4]) = po;
  }
  __syncthreads();

  // corr2 + outsum: wave handles ot in {2wv, 2wv+1}
#pragma unroll
  for (int oo = 0; oo < 2; ++oo) {
    const int ot = wv * 2 + oo;
    f32x4 c0 = {0.f, 0.f, 0.f, 0.f};
    f32x4 c1 = {0.f, 0.f, 0.f, 0.f};
    f32x4 c2 = {0.f, 0.f, 0.f, 0.f};
#pragma unroll
    for (int ks = 0; ks < 2; ++ks) {
      const int bb = ks * 32 + ksub;
      bf16x8 bo = *(const bf16x8*)(&OT[(ot * 16 + arow) * 72 + bb]);
      bf16x8 a0 = *(const bf16x8*)(&AT[arow * 72 + bb]);
      bf16x8 a1 = *(const bf16x8*)(&AT[(16 + arow) * 72 + bb]);
      bf16x8 a2 = *(const bf16x8*)(&AT[(32 + arow) * 72 + bb]);
      c0 = __builtin_amdgcn_mfma_f32_16x16x32_bf16(a0, bo, c0, 0, 0, 0);
      c1 = __builtin_amdgcn_mfma_f32_16x16x32_bf16(a1, bo, c1, 0, 0, 0);
      c2 = __builtin_amdgcn_mfma_f32_16x16x32_bf16(a2, bo, c2, 0, 0, 0);
    }
    // D: col(o)=arow, row(h)=m4*4+r
    float* cp = corr2_part + (size_t)bc * (HID * OUTD) + obase + ot * 16 + arow;
#pragma unroll
    for (int r = 0; r < 4; ++r) {
      cp[(size_t)(m4 * 4 + r) * OUTD] = c0[r];
      cp[(size_t)(16 + m4 * 4 + r) * OUTD] = c1[r];
    }
    if (m4 == 0)
      outsum_part[(size_t)bc * OUTD + obase + ot * 16 + arow] = c2[0];
  }
}

// ---------------------------------------------------------------------------
// K3b: deterministic reduce of corr2/outsum partials (256 slices).
// ---------------------------------------------------------------------------
__global__ __launch_bounds__(256) void k_red2(
    const float* __restrict__ corr2_part, const float* __restrict__ outsum_part,
    float* __restrict__ corr2, float* __restrict__ outsum) {
  const int e = blockIdx.x * 256 + threadIdx.x;
  float s = 0.f;
#pragma unroll 8
  for (int c = 0; c < NC2; ++c) s += corr2_part[(size_t)c * (HID * OUTD) + e];
  corr2[e] = s;
  if (e < OUTD) {
    float t = 0.f;
#pragma unroll 8
    for (int c = 0; c < NC2; ++c) t += outsum_part[(size_t)c * OUTD + e];
    outsum[e] = t;
  }
}

// ---------------------------------------------------------------------------
// K4: w1_new[h,i] = (w1[h,i] + dw1T[i,h]) / ||row h||_2 ; corr1T[h][i].
// ---------------------------------------------------------------------------
__global__ __launch_bounds__(256) void k_w1(
    const float* __restrict__ w1, const float* __restrict__ heb,
    const float* __restrict__ corr1T, const float* __restrict__ xsum,
    const float* __restrict__ actsum, float* __restrict__ w1out) {
  const int h = blockIdx.x;
  const int tid = threadIdx.x;
  const float ash = actsum[h];
  const float4* heb4 = (const float4*)heb;

  float val[8];
  float ss = 0.f;
#pragma unroll
  for (int r = 0; r < 8; ++r) {
    const int i = tid + 256 * r;
    float4 c = heb4[(size_t)i * HID + h];
    float v = w1[(size_t)h * IND + i] + 16384.0f * c.w +
              c.x * corr1T[(size_t)h * IND + i] + c.y * xsum[i] + c.z * ash;
    val[r] = v;
    ss += v * v;
  }

  __shared__ float red[256];
  red[tid] = ss;
  __syncthreads();
  for (int s = 128; s > 0; s >>= 1) {
    if (tid < s) red[tid] += red[tid + s];
    __syncthreads();
  }
  const float inv = 1.0f / sqrtf(red[0]);
#pragma unroll
  for (int r = 0; r < 8; ++r) {
    const int i = tid + 256 * r;
    w1out[(size_t)h * IND + i] = val[r] * inv;
  }
}

// ---------------------------------------------------------------------------
// K5: w2_new[o,h] = (w2[o,h] + dw2T[h,o]) / ||row o||_2
// ---------------------------------------------------------------------------
__global__ __launch_bounds__(256) void k_w2(
    const float* __restrict__ w2, const float* __restrict__ heb,
    const float* __restrict__ corr2, const float* __restrict__ actsum,
    const float* __restrict__ outsum, float* __restrict__ w2out) {
  const int o = blockIdx.x * 256 + threadIdx.x;
  const float oso = outsum[o];
  const float4* heb4 = (const float4*)heb;

  float val[HID];
  float ss = 0.f;
#pragma unroll
  for (int h = 0; h < HID; ++h) {
    float4 c = heb4[(size_t)(HID * IND) + (size_t)h * OUTD + o];
    float v = w2[(size_t)o * HID + h] + 16384.0f * c.w +
              c.x * corr2[(size_t)h * OUTD + o] + c.y * actsum[h] + c.z * oso;
    val[h] = v;
    ss += v * v;
  }
  const float inv = 1.0f / sqrtf(ss);
#pragma unroll
  for (int h = 0; h < HID; ++h) w2out[(size_t)o * HID + h] = val[h] * inv;
}

// ---------------------------------------------------------------------------
extern "C" void kernel_launch(void* const* d_in, const int* in_sizes, int n_in,
                              void* d_out, int out_size, void* d_ws,
                              size_t ws_size, hipStream_t stream) {
  const float* x   = (const float*)d_in[0];   // [16384, 2048]
  const float* w1  = (const float*)d_in[1];   // [32, 2048]
  const float* w2  = (const float*)d_in[2];   // [512, 32]
  const float* heb = (const float*)d_in[3];   // [81920, 4]

  float* out = (float*)d_out;                 // [16384, 512]
  float* w1o = out + (size_t)BATCH * OUTD;    // [32, 2048]
  float* w2o = w1o + (size_t)HID * IND;       // [512, 32]

  float* ws = (float*)d_ws;                   // ws ~537 MB; layout ~92 MB
  unsigned short* actH = (unsigned short*)ws;                    // 524288 us
  unsigned short* actL = actH + (size_t)BATCH * HID;             // 524288 us
  unsigned short* actT = actL + (size_t)BATCH * HID;             // 524288 us
  float* corr1T      = ws + (size_t)3 * BATCH * HID / 2;         // 65536
  float* corr2       = corr1T + (size_t)IND * HID;               // 16384
  float* xsum        = corr2 + (size_t)HID * OUTD;               // 2048
  float* actsum      = xsum + IND;                               // 32
  float* outsum      = actsum + HID;                             // 512
  float* act_part    = outsum + OUTD;                            // 2*524288
  float* corr1T_part = act_part + (size_t)2 * BATCH * HID;       // 256*65536
  float* xsum_part   = corr1T_part + (size_t)NC1 * IND * HID;    // 256*2048
  float* actsum_part = xsum_part + (size_t)NC1 * IND;            // 64*32
  float* corr2_part  = actsum_part + (size_t)NSA * HID;          // 256*16384
  float* outsum_part = corr2_part + (size_t)NC2 * HID * OUTD;    // 256*512

  k_act  <<<1024, 256, 0, stream>>>(x, w1, act_part);
  k_actc <<<64, 256, 0, stream>>>(act_part, actH, actL, actT, actsum_part);
  k_corr1<<<1024, 512, 0, stream>>>(x, actT, corr1T_part, xsum_part);
  k_red1 <<<256, 256, 0, stream>>>(corr1T_part, xsum_part, actsum_part,
                                   corr1T, xsum, actsum);
  k_fwd2m<<<1024, 256, 0, stream>>>(actH, actL, actT, w2, out, corr2_part,
                                    outsum_part);
  k_red2 <<<64, 256, 0, stream>>>(corr2_part, outsum_part, corr2, outsum);
  k_w1   <<<32, 256, 0, stream>>>(w1, heb, corr1T, xsum, actsum, w1o);
  k_w2   <<<2, 256, 0, stream>>>(w2, heb, corr2, actsum, outsum, w2o);
}

// Round 19
// 130.788 us; speedup vs baseline: 1.2330x; 1.1585x over previous
//
#include <hip/hip_runtime.h>
#include <math.h>

// Problem constants
constexpr int BATCH = 16384;
constexpr int IND   = 2048;   // INPUT
constexpr int HID   = 32;     // HIDDEN
constexpr int OUTD  = 512;    // OUTPUT

constexpr int NC1 = 128;      // corr1/xsum partial slices (b-chunks of 128)
constexpr int NSA = 64;       // actsum partial slices (k_actc blocks)
constexpr int NC2 = 256;      // corr2/outsum partial slices (b-chunks of 64)

constexpr int SA   = 136;     // ushort row stride, k_act tiles
constexpr int SXT  = 72;      // ushort row stride, k_corr1 xT tile (64 b)
constexpr int SATW = 136;     // ushort row stride, k_corr1 actT tile (128 b)

typedef __attribute__((ext_vector_type(8))) short bf16x8;
typedef __attribute__((ext_vector_type(4))) float f32x4;

__device__ __forceinline__ unsigned short f2bf(float f) {
  unsigned u = __float_as_uint(f);
  u += 0x7FFFu + ((u >> 16) & 1u);          // round-to-nearest-even
  return (unsigned short)(u >> 16);
}
__device__ __forceinline__ float bf2f(unsigned short h) {
  return __uint_as_float(((unsigned)h) << 16);
}
__device__ __forceinline__ void split2(float f, unsigned short& hi,
                                       unsigned short& lo) {
  hi = f2bf(f);
  lo = f2bf(f - bf2f(hi));
}
__device__ __forceinline__ int swzA(int row, int col) {
  return row * SA + (col ^ (((row >> 3) & 7) * 8));
}

// ---------------------------------------------------------------------------
// K0: pre-split w1/w2 to hi/lo bf16 ONCE. r18 re-split w1 in every k_act
// block (134 MB redundant w reads + half the staging VALU) and w2 in every
// k_fwd2m block. grid = 80: blocks 0..63 -> w1 (16384 float4), 64..79 -> w2.
// ---------------------------------------------------------------------------
__global__ __launch_bounds__(256) void k_cvtw(
    const float* __restrict__ w1, const float* __restrict__ w2,
    unsigned short* __restrict__ w1H, unsigned short* __restrict__ w1L,
    unsigned short* __restrict__ w2H, unsigned short* __restrict__ w2L) {
  const int bid = blockIdx.x;
  if (bid < 64) {
    const int g = bid * 256 + threadIdx.x;          // < 16384
    float4 v = ((const float4*)w1)[g];
    ushort4 h, l;
    split2(v.x, h.x, l.x); split2(v.y, h.y, l.y);
    split2(v.z, h.z, l.z); split2(v.w, h.w, l.w);
    ((ushort4*)w1H)[g] = h;
    ((ushort4*)w1L)[g] = l;
  } else {
    const int g = (bid - 64) * 256 + threadIdx.x;   // < 4096
    float4 v = ((const float4*)w2)[g];
    ushort4 h, l;
    split2(v.x, h.x, l.x); split2(v.y, h.y, l.y);
    split2(v.z, h.z, l.z); split2(v.w, h.w, l.w);
    ((ushort4*)w2H)[g] = h;
    ((ushort4*)w2L)[g] = l;
  }
}

// ---------------------------------------------------------------------------
// K1a: act partials = x @ w1T (no relu), split-bf16 MFMA. w1 staged from
// pre-split bf16 (no per-block split2). grid = 1024 = (bt x 32 rows) x kq.
// ---------------------------------------------------------------------------
__global__ __launch_bounds__(256, 4) void k_act(
    const float* __restrict__ x, const unsigned short* __restrict__ w1H,
    const unsigned short* __restrict__ w1L, float* __restrict__ act_part) {
  const int tid = threadIdx.x;
  const int kq = blockIdx.x & 1;
  const int bt = blockIdx.x >> 1;          // 0..511
  const int b0 = bt * 32;
  const int kbase = kq * 1024;
  const int lane = tid & 63;
  const int wv = tid >> 6;                 // 0..3
  const int arow = lane & 15;
  const int m4 = lane >> 4;                // 0..3
  const int ksub = m4 * 8;
  const int rt = wv & 1;
  const int ht = wv >> 1;

  __shared__ __align__(16) unsigned short XH[32 * SA];
  __shared__ __align__(16) unsigned short XL[32 * SA];
  __shared__ __align__(16) unsigned short WH[32 * SA];
  __shared__ __align__(16) unsigned short WL[32 * SA];

  const int rp = tid >> 4;
  const int kg = (tid & 15) * 8;

  float4 px0a, px0b, px1a, px1b;
  bf16x8 pwh0, pwl0, pwh1, pwl1;

#define LOADA(K0)                                                          \
  {                                                                        \
    const float* xr0 = x + (size_t)(b0 + 2 * rp) * IND + kbase + (K0) + kg;\
    const float* xr1 = xr0 + IND;                                          \
    px0a = *(const float4*)(xr0);                                          \
    px0b = *(const float4*)(xr0 + 4);                                      \
    px1a = *(const float4*)(xr1);                                          \
    px1b = *(const float4*)(xr1 + 4);                                      \
    const size_t wo = (size_t)(2 * rp) * IND + kbase + (K0) + kg;          \
    pwh0 = *(const bf16x8*)(&w1H[wo]);                                     \
    pwl0 = *(const bf16x8*)(&w1L[wo]);                                     \
    pwh1 = *(const bf16x8*)(&w1H[wo + IND]);                               \
    pwl1 = *(const bf16x8*)(&w1L[wo + IND]);                               \
  }

#define PUTX(ROW, COL, V)                                            \
  {                                                                  \
    ushort4 h_, l_;                                                  \
    split2((V).x, h_.x, l_.x); split2((V).y, h_.y, l_.y);            \
    split2((V).z, h_.z, l_.z); split2((V).w, h_.w, l_.w);            \
    *(ushort4*)(&XH[swzA((ROW), (COL))]) = h_;                       \
    *(ushort4*)(&XL[swzA((ROW), (COL))]) = l_;                       \
  }

#define STOREA                                                       \
  {                                                                  \
    PUTX(2 * rp, kg, px0a);                                          \
    PUTX(2 * rp, kg + 4, px0b);                                      \
    PUTX(2 * rp + 1, kg, px1a);                                      \
    PUTX(2 * rp + 1, kg + 4, px1b);                                  \
    *(bf16x8*)(&WH[swzA(2 * rp, kg)]) = pwh0;                        \
    *(bf16x8*)(&WL[swzA(2 * rp, kg)]) = pwl0;                        \
    *(bf16x8*)(&WH[swzA(2 * rp + 1, kg)]) = pwh1;                    \
    *(bf16x8*)(&WL[swzA(2 * rp + 1, kg)]) = pwl1;                    \
  }

  f32x4 accA = {0.f, 0.f, 0.f, 0.f};
  LOADA(0);

  for (int kc = 0; kc < 8; ++kc) {
    __syncthreads();
    STOREA;
    __syncthreads();
    if (kc < 7) LOADA((kc + 1) * 128);
    const int xrow = rt * 16 + arow;
    const int wrow = ht * 16 + arow;
#pragma unroll
    for (int ks = 0; ks < 4; ++ks) {
      const int kk = ks * 32 + ksub;
      bf16x8 ah = *(const bf16x8*)(&XH[swzA(xrow, kk)]);
      bf16x8 al = *(const bf16x8*)(&XL[swzA(xrow, kk)]);
      bf16x8 bh = *(const bf16x8*)(&WH[swzA(wrow, kk)]);
      bf16x8 bl_ = *(const bf16x8*)(&WL[swzA(wrow, kk)]);
      accA = __builtin_amdgcn_mfma_f32_16x16x32_bf16(ah, bh, accA, 0, 0, 0);
      accA = __builtin_amdgcn_mfma_f32_16x16x32_bf16(ah, bl_, accA, 0, 0, 0);
      accA = __builtin_amdgcn_mfma_f32_16x16x32_bf16(al, bh, accA, 0, 0, 0);
    }
  }

  const int bl = rt * 16 + (m4 << 2);
  const int h = ht * 16 + arow;
  float* p = act_part + (size_t)kq * (BATCH * HID);
#pragma unroll
  for (int r = 0; r < 4; ++r)
    p[(size_t)(b0 + bl + r) * HID + h] = accA[r];
}

// ---------------------------------------------------------------------------
// K1b: combine 2 K-half partials -> relu -> actH/actL bf16 [b][h] + actT
// bf16 [h][b] + actsum partials. r18-verbatim. grid = 64 x 256.
// ---------------------------------------------------------------------------
__global__ __launch_bounds__(256) void k_actc(
    const float* __restrict__ act_part,
    unsigned short* __restrict__ actH, unsigned short* __restrict__ actL,
    unsigned short* __restrict__ actT, float* __restrict__ actsum_part) {
  const int tid = threadIdx.x;
  const int blk = blockIdx.x;              // 0..63
  const int b0 = blk * 256;

  __shared__ unsigned short asT[32][264];
  __shared__ float red[256][4];

  const float4* p0 = (const float4*)act_part;
  const float4* p1 = p0 + (size_t)BATCH * HID / 4;

  const int hq = tid & 7;
  float4 s{0.f, 0.f, 0.f, 0.f};
#pragma unroll
  for (int r = 0; r < 8; ++r) {
    const int e4 = r * 256 + tid;
    const int b = e4 >> 3;
    const size_t g = (size_t)(b0 + b) * 8 + hq;
    float4 a = p0[g];
    float4 c = p1[g];
    a.x = fmaxf(a.x + c.x, 0.f);  a.y = fmaxf(a.y + c.y, 0.f);
    a.z = fmaxf(a.z + c.z, 0.f);  a.w = fmaxf(a.w + c.w, 0.f);
    ushort4 hh, ll;
    split2(a.x, hh.x, ll.x); split2(a.y, hh.y, ll.y);
    split2(a.z, hh.z, ll.z); split2(a.w, hh.w, ll.w);
    *(ushort4*)(&actH[g * 4]) = hh;
    *(ushort4*)(&actL[g * 4]) = ll;
    asT[hq * 4 + 0][b] = hh.x;
    asT[hq * 4 + 1][b] = hh.y;
    asT[hq * 4 + 2][b] = hh.z;
    asT[hq * 4 + 3][b] = hh.w;
    s.x += a.x; s.y += a.y; s.z += a.z; s.w += a.w;
  }
  red[tid][0] = s.x; red[tid][1] = s.y;
  red[tid][2] = s.z; red[tid][3] = s.w;
  __syncthreads();

#pragma unroll
  for (int r = 0; r < 4; ++r) {
    const int slot = r * 256 + tid;
    const int hrow = slot >> 5;
    const int bseg = (slot & 31) * 8;
    bf16x8 v = *(const bf16x8*)(&asT[hrow][bseg]);
    *(bf16x8*)(&actT[(size_t)hrow * BATCH + b0 + bseg]) = v;
  }
  if (tid < 32) {
    const int q = tid >> 2, j = tid & 3;
    float t = 0.f;
#pragma unroll
    for (int sx = 0; sx < 32; ++sx) t += red[q + 8 * sx][j];
    actsum_part[blk * HID + tid] = t;
  }
}

// ---------------------------------------------------------------------------
// K1c: corr1T_part = x^T @ act (+ xsum via ones tile). Each block now
// ACCUMULATES TWO 64-b halves per slice in C-registers before writing:
// NC1 256->128 slices halves partial traffic (67->33.5 MB round trip).
// grid = 512 = (bc 0..127 b-chunks of 128) x (iq 0..3), 512 thr.
// AT widened to 128 b (staged once); XT re-staged per (ic, half).
// ---------------------------------------------------------------------------
__global__ __launch_bounds__(512, 4) void k_corr1(
    const float* __restrict__ x, const unsigned short* __restrict__ actT,
    float* __restrict__ corr1T_part, float* __restrict__ xsum_part) {
  const int tid = threadIdx.x;
  const int bc = blockIdx.x >> 2;          // 0..127
  const int iq = blockIdx.x & 3;           // 0..3
  const int b0 = bc * 128;
  const int ibase = iq * 512;
  const int lane = tid & 63;
  const int wv = tid >> 6;                 // 0..7
  const int arow = lane & 15;
  const int m4 = lane >> 4;
  const int ksub = m4 * 8;
  const int it = wv * 16;

  __shared__ __align__(16) unsigned short XT[128 * SXT];
  __shared__ __align__(16) unsigned short AT[48 * SATW];

  // ones rows 32..47 (cover all 128 b + pad)
  for (int e = tid; e < 16 * SATW; e += 512)
    AT[32 * SATW + e] = (unsigned short)0x3F80;
  // stage actT [32 h][128 b], swizzled per 8-granule
  if (tid < 256) {
    const int hrow = tid >> 3;             // 0..31
    const int bq16 = (tid & 7) * 16;       // 0..112
    const int sw = ((hrow >> 3) & 7) * 8;
#pragma unroll
    for (int j = 0; j < 2; ++j) {
      const int boff = bq16 + 8 * j;
      bf16x8 v = *(const bf16x8*)(&actT[(size_t)hrow * BATCH + b0 + boff]);
      *(bf16x8*)(&AT[hrow * SATW + (boff ^ sw)]) = v;
    }
  }

  const int ig = tid & 15;                 // i-group (8 i)
  const int bq = tid >> 4;                 // 0..31 -> half-local rows 2bq,2bq+1

  float4 xa, xb, ya, yb;

#define LOADC(IC, HF)                                                    \
  {                                                                      \
    const int icol = ibase + (IC) * 128 + ig * 8;                        \
    const float* r0 = x + (size_t)(b0 + 64 * (HF) + 2 * bq) * IND + icol;\
    const float* r1 = r0 + IND;                                          \
    xa = *(const float4*)(r0); xb = *(const float4*)(r0 + 4);            \
    ya = *(const float4*)(r1); yb = *(const float4*)(r1 + 4);            \
  }

#define STC                                                                \
  {                                                                        \
    const int qb = (2 * bq) ^ ((ig & 7) * 8);                              \
    unsigned short* basew = &XT[(size_t)(ig * 8) * SXT + qb];              \
    ushort2 p;                                                             \
    p.x = f2bf(xa.x); p.y = f2bf(ya.x); *(ushort2*)(basew + 0 * SXT) = p;  \
    p.x = f2bf(xa.y); p.y = f2bf(ya.y); *(ushort2*)(basew + 1 * SXT) = p;  \
    p.x = f2bf(xa.z); p.y = f2bf(ya.z); *(ushort2*)(basew + 2 * SXT) = p;  \
    p.x = f2bf(xa.w); p.y = f2bf(ya.w); *(ushort2*)(basew + 3 * SXT) = p;  \
    p.x = f2bf(xb.x); p.y = f2bf(yb.x); *(ushort2*)(basew + 4 * SXT) = p;  \
    p.x = f2bf(xb.y); p.y = f2bf(yb.y); *(ushort2*)(basew + 5 * SXT) = p;  \
    p.x = f2bf(xb.z); p.y = f2bf(yb.z); *(ushort2*)(basew + 6 * SXT) = p;  \
    p.x = f2bf(xb.w); p.y = f2bf(yb.w); *(ushort2*)(basew + 7 * SXT) = p;  \
  }

  const int swzr = (((it + arow) >> 3) & 7) * 8;
  const int swze0 = ((arow >> 3) & 7) * 8;
  const int swze1 = (((16 + arow) >> 3) & 7) * 8;

  LOADC(0, 0);
  for (int ic = 0; ic < 4; ++ic) {
    f32x4 c00 = {0.f, 0.f, 0.f, 0.f};
    f32x4 c01 = {0.f, 0.f, 0.f, 0.f};
    f32x4 c02 = {0.f, 0.f, 0.f, 0.f};
#pragma unroll
    for (int hf = 0; hf < 2; ++hf) {
      __syncthreads();                     // prev XT readers done (+AT/ones)
      STC;
      __syncthreads();
      if (!(ic == 3 && hf == 1)) {         // issue next stage's loads EARLY
        const int nic = (hf == 1) ? ic + 1 : ic;
        const int nhf = hf ^ 1;
        LOADC(nic, nhf);
      }
#pragma unroll
      for (int bs = 0; bs < 2; ++bs) {
        const int bb = bs * 32 + ksub;     // within-64
        const int bb2 = 64 * hf + bb;      // within-128 (AT index)
        bf16x8 a = *(const bf16x8*)(&XT[(it + arow) * SXT + (bb ^ swzr)]);
        bf16x8 e0 = *(const bf16x8*)(&AT[arow * SATW + (bb2 ^ swze0)]);
        bf16x8 e1 = *(const bf16x8*)(&AT[(16 + arow) * SATW + (bb2 ^ swze1)]);
        bf16x8 e2 = *(const bf16x8*)(&AT[(32 + arow) * SATW + bb2]);
        c00 = __builtin_amdgcn_mfma_f32_16x16x32_bf16(a, e0, c00, 0, 0, 0);
        c01 = __builtin_amdgcn_mfma_f32_16x16x32_bf16(a, e1, c01, 0, 0, 0);
        c02 = __builtin_amdgcn_mfma_f32_16x16x32_bf16(a, e2, c02, 0, 0, 0);
      }
    }
    float* basep = corr1T_part + (size_t)bc * (IND * HID);
    const int gi = ibase + ic * 128 + it + (m4 << 2);
    *(f32x4*)(basep + (size_t)arow * IND + gi) = c00;
    *(f32x4*)(basep + (size_t)(16 + arow) * IND + gi) = c01;
    if (arow == 0)
      *(f32x4*)(xsum_part + (size_t)bc * IND + gi) = c02;
  }
}

// ---------------------------------------------------------------------------
// K1d: deterministic reduce (corr1T/xsum: 128 slices, actsum: 64).
// ---------------------------------------------------------------------------
__global__ __launch_bounds__(256) void k_red1(
    const float* __restrict__ c1p, const float* __restrict__ xsp,
    const float* __restrict__ asp,
    float* __restrict__ corr1T, float* __restrict__ xsum,
    float* __restrict__ actsum) {
  const int e = blockIdx.x * 256 + threadIdx.x;
  float s = 0.f;
#pragma unroll 8
  for (int c = 0; c < NC1; ++c) s += c1p[(size_t)c * (IND * HID) + e];
  corr1T[e] = s;
  if (e < IND) {
    float t = 0.f;
#pragma unroll 8
    for (int c = 0; c < NC1; ++c) t += xsp[(size_t)c * IND + e];
    xsum[e] = t;
  }
  if (e < HID) {
    float t = 0.f;
#pragma unroll 8
    for (int c = 0; c < NSA; ++c) t += asp[(size_t)c * HID + e];
    actsum[e] = t;
  }
}

// ---------------------------------------------------------------------------
// K3: layer-2 MFMA (r18-verified). w2 now staged from pre-split bf16.
// grid = 1024 = (bc 0..255 x 64 b) x (og 0..3 x 128 o); 256 thr.
// ---------------------------------------------------------------------------
__global__ __launch_bounds__(256, 2) void k_fwd2m(
    const unsigned short* __restrict__ actH,
    const unsigned short* __restrict__ actL,
    const unsigned short* __restrict__ actT,
    const unsigned short* __restrict__ w2H,
    const unsigned short* __restrict__ w2L,
    float* __restrict__ out, float* __restrict__ corr2_part,
    float* __restrict__ outsum_part) {
  const int tid = threadIdx.x;
  const int bc = blockIdx.x >> 2;          // 0..255
  const int og = blockIdx.x & 3;           // 0..3
  const int b0 = bc * 64;
  const int obase = og * 128;
  const int lane = tid & 63;
  const int wv = tid >> 6;                 // 0..3
  const int arow = lane & 15;
  const int m4 = lane >> 4;
  const int ksub = m4 * 8;

  __shared__ __align__(16) unsigned short W2H[128 * 40];
  __shared__ __align__(16) unsigned short W2L[128 * 40];
  __shared__ __align__(16) unsigned short AH[64 * 40];
  __shared__ __align__(16) unsigned short AL[64 * 40];
  __shared__ __align__(16) unsigned short AT[48 * 72];
  __shared__ __align__(16) unsigned short OT[128 * 72];

  {  // stage w2 hi/lo from pre-split global
    const int r2 = tid >> 1, hh = (tid & 1) * 16;
    const size_t wo = (size_t)(obase + r2) * HID + hh;
    *(bf16x8*)(&W2H[r2 * 40 + hh]) = *(const bf16x8*)(&w2H[wo]);
    *(bf16x8*)(&W2H[r2 * 40 + hh + 8]) = *(const bf16x8*)(&w2H[wo + 8]);
    *(bf16x8*)(&W2L[r2 * 40 + hh]) = *(const bf16x8*)(&w2L[wo]);
    *(bf16x8*)(&W2L[r2 * 40 + hh + 8]) = *(const bf16x8*)(&w2L[wo + 8]);
  }
  {  // stage act hi/lo [64 b][32 h]
    const int b = tid >> 2, q = (tid & 3) * 8;
    *(bf16x8*)(&AH[b * 40 + q]) =
        *(const bf16x8*)(&actH[(size_t)(b0 + b) * HID + q]);
    *(bf16x8*)(&AL[b * 40 + q]) =
        *(const bf16x8*)(&actL[(size_t)(b0 + b) * HID + q]);
  }
  {  // stage actT [32 h][64 b] + ones rows 32..47
    const int h = tid >> 3, seg = (tid & 7) * 8;
    *(bf16x8*)(&AT[h * 72 + seg]) =
        *(const bf16x8*)(&actT[(size_t)h * BATCH + b0 + seg]);
  }
  for (int e = tid; e < 16 * 72; e += 256)
    AT[32 * 72 + e] = (unsigned short)0x3F80;
  __syncthreads();

  // forward: wave = b-tile
  const int bt = wv;
  bf16x8 fah = *(const bf16x8*)(&AH[(bt * 16 + arow) * 40 + ksub]);
  bf16x8 fal = *(const bf16x8*)(&AL[(bt * 16 + arow) * 40 + ksub]);
#pragma unroll
  for (int ot = 0; ot < 8; ++ot) {
    bf16x8 wbh = *(const bf16x8*)(&W2H[(ot * 16 + arow) * 40 + ksub]);
    bf16x8 wbl = *(const bf16x8*)(&W2L[(ot * 16 + arow) * 40 + ksub]);
    f32x4 z = {0.f, 0.f, 0.f, 0.f};
    z = __builtin_amdgcn_mfma_f32_16x16x32_bf16(fah, wbh, z, 0, 0, 0);
    z = __builtin_amdgcn_mfma_f32_16x16x32_bf16(fah, wbl, z, 0, 0, 0);
    z = __builtin_amdgcn_mfma_f32_16x16x32_bf16(fal, wbh, z, 0, 0, 0);
    ushort4 po;
    {
      float ov0 = 1.0f / (1.0f + __expf(-z[0])) - 0.4f;
      float ov1 = 1.0f / (1.0f + __expf(-z[1])) - 0.4f;
      float ov2 = 1.0f / (1.0f + __expf(-z[2])) - 0.4f;
      float ov3 = 1.0f / (1.0f + __expf(-z[3])) - 0.4f;
      const size_t ob = (size_t)(b0 + bt * 16 + m4 * 4) * OUTD +
                        obase + ot * 16 + arow;
      out[ob + 0 * OUTD] = ov0;
      out[ob + 1 * OUTD] = ov1;
      out[ob + 2 * OUTD] = ov2;
      out[ob + 3 * OUTD] = ov3;
      po.x = f2bf(ov0); po.y = f2bf(ov1); po.z = f2bf(ov2); po.w = f2bf(ov3);
    }
    *(ushort4*)(&OT[(ot * 16 + arow) * 72 + bt * 16 + m4 * 4]) = po;
  }
  __syncthreads();

  // corr2 + outsum: wave handles ot in {2wv, 2wv+1}
#pragma unroll
  for (int oo = 0; oo < 2; ++oo) {
    const int ot = wv * 2 + oo;
    f32x4 c0 = {0.f, 0.f, 0.f, 0.f};
    f32x4 c1 = {0.f, 0.f, 0.f, 0.f};
    f32x4 c2 = {0.f, 0.f, 0.f, 0.f};
#pragma unroll
    for (int ks = 0; ks < 2; ++ks) {
      const int bb = ks * 32 + ksub;
      bf16x8 bo = *(const bf16x8*)(&OT[(ot * 16 + arow) * 72 + bb]);
      bf16x8 a0 = *(const bf16x8*)(&AT[arow * 72 + bb]);
      bf16x8 a1 = *(const bf16x8*)(&AT[(16 + arow) * 72 + bb]);
      bf16x8 a2 = *(const bf16x8*)(&AT[(32 + arow) * 72 + bb]);
      c0 = __builtin_amdgcn_mfma_f32_16x16x32_bf16(a0, bo, c0, 0, 0, 0);
      c1 = __builtin_amdgcn_mfma_f32_16x16x32_bf16(a1, bo, c1, 0, 0, 0);
      c2 = __builtin_amdgcn_mfma_f32_16x16x32_bf16(a2, bo, c2, 0, 0, 0);
    }
    float* cp = corr2_part + (size_t)bc * (HID * OUTD) + obase + ot * 16 + arow;
#pragma unroll
    for (int r = 0; r < 4; ++r) {
      cp[(size_t)(m4 * 4 + r) * OUTD] = c0[r];
      cp[(size_t)(16 + m4 * 4 + r) * OUTD] = c1[r];
    }
    if (m4 == 0)
      outsum_part[(size_t)bc * OUTD + obase + ot * 16 + arow] = c2[0];
  }
}

// ---------------------------------------------------------------------------
// K3b: deterministic reduce of corr2/outsum partials (256 slices).
// ---------------------------------------------------------------------------
__global__ __launch_bounds__(256) void k_red2(
    const float* __restrict__ corr2_part, const float* __restrict__ outsum_part,
    float* __restrict__ corr2, float* __restrict__ outsum) {
  const int e = blockIdx.x * 256 + threadIdx.x;
  float s = 0.f;
#pragma unroll 8
  for (int c = 0; c < NC2; ++c) s += corr2_part[(size_t)c * (HID * OUTD) + e];
  corr2[e] = s;
  if (e < OUTD) {
    float t = 0.f;
#pragma unroll 8
    for (int c = 0; c < NC2; ++c) t += outsum_part[(size_t)c * OUTD + e];
    outsum[e] = t;
  }
}

// ---------------------------------------------------------------------------
// K4: w1_new[h,i] = (w1[h,i] + dw1T[i,h]) / ||row h||_2 ; corr1T[h][i].
// ---------------------------------------------------------------------------
__global__ __launch_bounds__(256) void k_w1(
    const float* __restrict__ w1, const float* __restrict__ heb,
    const float* __restrict__ corr1T, const float* __restrict__ xsum,
    const float* __restrict__ actsum, float* __restrict__ w1out) {
  const int h = blockIdx.x;
  const int tid = threadIdx.x;
  const float ash = actsum[h];
  const float4* heb4 = (const float4*)heb;

  float val[8];
  float ss = 0.f;
#pragma unroll
  for (int r = 0; r < 8; ++r) {
    const int i = tid + 256 * r;
    float4 c = heb4[(size_t)i * HID + h];
    float v = w1[(size_t)h * IND + i] + 16384.0f * c.w +
              c.x * corr1T[(size_t)h * IND + i] + c.y * xsum[i] + c.z * ash;
    val[r] = v;
    ss += v * v;
  }

  __shared__ float red[256];
  red[tid] = ss;
  __syncthreads();
  for (int s = 128; s > 0; s >>= 1) {
    if (tid < s) red[tid] += red[tid + s];
    __syncthreads();
  }
  const float inv = 1.0f / sqrtf(red[0]);
#pragma unroll
  for (int r = 0; r < 8; ++r) {
    const int i = tid + 256 * r;
    w1out[(size_t)h * IND + i] = val[r] * inv;
  }
}

// ---------------------------------------------------------------------------
// K5: w2_new[o,h] = (w2[o,h] + dw2T[h,o]) / ||row o||_2
// ---------------------------------------------------------------------------
__global__ __launch_bounds__(256) void k_w2(
    const float* __restrict__ w2, const float* __restrict__ heb,
    const float* __restrict__ corr2, const float* __restrict__ actsum,
    const float* __restrict__ outsum, float* __restrict__ w2out) {
  const int o = blockIdx.x * 256 + threadIdx.x;
  const float oso = outsum[o];
  const float4* heb4 = (const float4*)heb;

  float val[HID];
  float ss = 0.f;
#pragma unroll
  for (int h = 0; h < HID; ++h) {
    float4 c = heb4[(size_t)(HID * IND) + (size_t)h * OUTD + o];
    float v = w2[(size_t)o * HID + h] + 16384.0f * c.w +
              c.x * corr2[(size_t)h * OUTD + o] + c.y * actsum[h] + c.z * oso;
    val[h] = v;
    ss += v * v;
  }
  const float inv = 1.0f / sqrtf(ss);
#pragma unroll
  for (int h = 0; h < HID; ++h) w2out[(size_t)o * HID + h] = val[h] * inv;
}

// ---------------------------------------------------------------------------
extern "C" void kernel_launch(void* const* d_in, const int* in_sizes, int n_in,
                              void* d_out, int out_size, void* d_ws,
                              size_t ws_size, hipStream_t stream) {
  const float* x   = (const float*)d_in[0];   // [16384, 2048]
  const float* w1  = (const float*)d_in[1];   // [32, 2048]
  const float* w2  = (const float*)d_in[2];   // [512, 32]
  const float* heb = (const float*)d_in[3];   // [81920, 4]

  float* out = (float*)d_out;                 // [16384, 512]
  float* w1o = out + (size_t)BATCH * OUTD;    // [32, 2048]
  float* w2o = w1o + (size_t)HID * IND;       // [512, 32]

  float* ws = (float*)d_ws;                   // ws ~537 MB; layout ~60 MB
  unsigned short* actH = (unsigned short*)ws;                      // 262144 f
  unsigned short* actL = actH + (size_t)BATCH * HID;               // 262144 f
  unsigned short* actT = actL + (size_t)BATCH * HID;               // 262144 f
  unsigned short* w1H  = actT + (size_t)BATCH * HID;               // 32768 f
  unsigned short* w1L  = w1H + (size_t)HID * IND;                  // 32768 f
  unsigned short* w2H  = w1L + (size_t)HID * IND;                  // 8192 f
  unsigned short* w2L  = w2H + (size_t)OUTD * HID;                 // 8192 f
  float* corr1T      = (float*)(w2L + (size_t)OUTD * HID);         // 65536
  float* corr2       = corr1T + (size_t)IND * HID;                 // 16384
  float* xsum        = corr2 + (size_t)HID * OUTD;                 // 2048
  float* actsum      = xsum + IND;                                 // 32
  float* outsum      = actsum + HID;                               // 512
  float* act_part    = outsum + OUTD;                              // 2*524288
  float* corr1T_part = act_part + (size_t)2 * BATCH * HID;         // 128*65536
  float* xsum_part   = corr1T_part + (size_t)NC1 * IND * HID;      // 128*2048
  float* actsum_part = xsum_part + (size_t)NC1 * IND;              // 64*32
  float* corr2_part  = actsum_part + (size_t)NSA * HID;            // 256*16384
  float* outsum_part = corr2_part + (size_t)NC2 * HID * OUTD;      // 256*512

  k_cvtw <<<80, 256, 0, stream>>>(w1, w2, w1H, w1L, w2H, w2L);
  k_act  <<<1024, 256, 0, stream>>>(x, w1H, w1L, act_part);
  k_actc <<<64, 256, 0, stream>>>(act_part, actH, actL, actT, actsum_part);
  k_corr1<<<512, 512, 0, stream>>>(x, actT, corr1T_part, xsum_part);
  k_red1 <<<256, 256, 0, stream>>>(corr1T_part, xsum_part, actsum_part,
                                   corr1T, xsum, actsum);
  k_fwd2m<<<1024, 256, 0, stream>>>(actH, actL, actT, w2H, w2L, out,
                                    corr2_part, outsum_part);
  k_red2 <<<64, 256, 0, stream>>>(corr2_part, outsum_part, corr2, outsum);
  k_w1   <<<32, 256, 0, stream>>>(w1, heb, corr1T, xsum, actsum, w1o);
  k_w2   <<<2, 256, 0, stream>>>(w2, heb, corr2, actsum, outsum, w2o);
}

// Round 20
// 127.559 us; speedup vs baseline: 1.2642x; 1.0253x over previous
//
#include <hip/hip_runtime.h>
#include <math.h>

// Problem constants
constexpr int BATCH = 16384;
constexpr int IND   = 2048;   // INPUT
constexpr int HID   = 32;     // HIDDEN
constexpr int OUTD  = 512;    // OUTPUT

constexpr int NC1 = 128;      // corr1/xsum partial slices (b-chunks of 128)
constexpr int NSA = 64;       // actsum partial slices (k_actc blocks)
constexpr int NC2 = 128;      // corr2/outsum partial slices (b-chunks of 128)

constexpr int SA   = 136;     // ushort row stride, k_act tiles
constexpr int SXT  = 72;      // ushort row stride, k_corr1 xT tile (64 b)
constexpr int SATW = 136;     // ushort row stride, k_corr1 actT tile (128 b)

typedef __attribute__((ext_vector_type(8))) short bf16x8;
typedef __attribute__((ext_vector_type(4))) float f32x4;

__device__ __forceinline__ unsigned short f2bf(float f) {
  unsigned u = __float_as_uint(f);
  u += 0x7FFFu + ((u >> 16) & 1u);          // round-to-nearest-even
  return (unsigned short)(u >> 16);
}
__device__ __forceinline__ float bf2f(unsigned short h) {
  return __uint_as_float(((unsigned)h) << 16);
}
__device__ __forceinline__ void split2(float f, unsigned short& hi,
                                       unsigned short& lo) {
  hi = f2bf(f);
  lo = f2bf(f - bf2f(hi));
}
__device__ __forceinline__ int swzA(int row, int col) {
  return row * SA + (col ^ (((row >> 3) & 7) * 8));
}

// ---------------------------------------------------------------------------
// K0: pre-split w1/w2 to hi/lo bf16 once (r19-verified).
// ---------------------------------------------------------------------------
__global__ __launch_bounds__(256) void k_cvtw(
    const float* __restrict__ w1, const float* __restrict__ w2,
    unsigned short* __restrict__ w1H, unsigned short* __restrict__ w1L,
    unsigned short* __restrict__ w2H, unsigned short* __restrict__ w2L) {
  const int bid = blockIdx.x;
  if (bid < 64) {
    const int g = bid * 256 + threadIdx.x;          // < 16384
    float4 v = ((const float4*)w1)[g];
    ushort4 h, l;
    split2(v.x, h.x, l.x); split2(v.y, h.y, l.y);
    split2(v.z, h.z, l.z); split2(v.w, h.w, l.w);
    ((ushort4*)w1H)[g] = h;
    ((ushort4*)w1L)[g] = l;
  } else {
    const int g = (bid - 64) * 256 + threadIdx.x;   // < 4096
    float4 v = ((const float4*)w2)[g];
    ushort4 h, l;
    split2(v.x, h.x, l.x); split2(v.y, h.y, l.y);
    split2(v.z, h.z, l.z); split2(v.w, h.w, l.w);
    ((ushort4*)w2H)[g] = h;
    ((ushort4*)w2L)[g] = l;
  }
}

// ---------------------------------------------------------------------------
// K1a: act partials = x @ w1T, split-bf16 MFMA (r19-verified). NOW ALSO
// EMITS xH bf16 [b][k] (the hi-split it already computes): 67 MB coalesced
// fire-and-forget write lets k_corr1 read bf16 (half traffic, no f2bf).
// grid = 1024 = (bt x 32 rows) x kq; (256,4).
// ---------------------------------------------------------------------------
__global__ __launch_bounds__(256, 4) void k_act(
    const float* __restrict__ x, const unsigned short* __restrict__ w1H,
    const unsigned short* __restrict__ w1L, float* __restrict__ act_part,
    unsigned short* __restrict__ xH) {
  const int tid = threadIdx.x;
  const int kq = blockIdx.x & 1;
  const int bt = blockIdx.x >> 1;          // 0..511
  const int b0 = bt * 32;
  const int kbase = kq * 1024;
  const int lane = tid & 63;
  const int wv = tid >> 6;                 // 0..3
  const int arow = lane & 15;
  const int m4 = lane >> 4;                // 0..3
  const int ksub = m4 * 8;
  const int rt = wv & 1;
  const int ht = wv >> 1;

  __shared__ __align__(16) unsigned short XH[32 * SA];
  __shared__ __align__(16) unsigned short XL[32 * SA];
  __shared__ __align__(16) unsigned short WH[32 * SA];
  __shared__ __align__(16) unsigned short WL[32 * SA];

  const int rp = tid >> 4;
  const int kg = (tid & 15) * 8;

  float4 px0a, px0b, px1a, px1b;
  bf16x8 pwh0, pwl0, pwh1, pwl1;

#define LOADA(K0)                                                          \
  {                                                                        \
    const float* xr0 = x + (size_t)(b0 + 2 * rp) * IND + kbase + (K0) + kg;\
    const float* xr1 = xr0 + IND;                                          \
    px0a = *(const float4*)(xr0);                                          \
    px0b = *(const float4*)(xr0 + 4);                                      \
    px1a = *(const float4*)(xr1);                                          \
    px1b = *(const float4*)(xr1 + 4);                                      \
    const size_t wo = (size_t)(2 * rp) * IND + kbase + (K0) + kg;          \
    pwh0 = *(const bf16x8*)(&w1H[wo]);                                     \
    pwl0 = *(const bf16x8*)(&w1L[wo]);                                     \
    pwh1 = *(const bf16x8*)(&w1H[wo + IND]);                               \
    pwl1 = *(const bf16x8*)(&w1L[wo + IND]);                               \
  }

#define PUTX2(ROW, COL, V, GK)                                       \
  {                                                                  \
    ushort4 h_, l_;                                                  \
    split2((V).x, h_.x, l_.x); split2((V).y, h_.y, l_.y);            \
    split2((V).z, h_.z, l_.z); split2((V).w, h_.w, l_.w);            \
    *(ushort4*)(&XH[swzA((ROW), (COL))]) = h_;                       \
    *(ushort4*)(&XL[swzA((ROW), (COL))]) = l_;                       \
    *(ushort4*)(&xH[(size_t)(b0 + (ROW)) * IND + (GK) + (COL)]) = h_;\
  }

#define STOREA(GK)                                                   \
  {                                                                  \
    PUTX2(2 * rp, kg, px0a, GK);                                     \
    PUTX2(2 * rp, kg + 4, px0b, GK);                                 \
    PUTX2(2 * rp + 1, kg, px1a, GK);                                 \
    PUTX2(2 * rp + 1, kg + 4, px1b, GK);                             \
    *(bf16x8*)(&WH[swzA(2 * rp, kg)]) = pwh0;                        \
    *(bf16x8*)(&WL[swzA(2 * rp, kg)]) = pwl0;                        \
    *(bf16x8*)(&WH[swzA(2 * rp + 1, kg)]) = pwh1;                    \
    *(bf16x8*)(&WL[swzA(2 * rp + 1, kg)]) = pwl1;                    \
  }

  f32x4 accA = {0.f, 0.f, 0.f, 0.f};
  LOADA(0);

  for (int kc = 0; kc < 8; ++kc) {
    __syncthreads();
    STOREA(kbase + kc * 128);
    __syncthreads();
    if (kc < 7) LOADA((kc + 1) * 128);
    const int xrow = rt * 16 + arow;
    const int wrow = ht * 16 + arow;
#pragma unroll
    for (int ks = 0; ks < 4; ++ks) {
      const int kk = ks * 32 + ksub;
      bf16x8 ah = *(const bf16x8*)(&XH[swzA(xrow, kk)]);
      bf16x8 al = *(const bf16x8*)(&XL[swzA(xrow, kk)]);
      bf16x8 bh = *(const bf16x8*)(&WH[swzA(wrow, kk)]);
      bf16x8 bl_ = *(const bf16x8*)(&WL[swzA(wrow, kk)]);
      accA = __builtin_amdgcn_mfma_f32_16x16x32_bf16(ah, bh, accA, 0, 0, 0);
      accA = __builtin_amdgcn_mfma_f32_16x16x32_bf16(ah, bl_, accA, 0, 0, 0);
      accA = __builtin_amdgcn_mfma_f32_16x16x32_bf16(al, bh, accA, 0, 0, 0);
    }
  }

  const int bl = rt * 16 + (m4 << 2);
  const int h = ht * 16 + arow;
  float* p = act_part + (size_t)kq * (BATCH * HID);
#pragma unroll
  for (int r = 0; r < 4; ++r)
    p[(size_t)(b0 + bl + r) * HID + h] = accA[r];
}

// ---------------------------------------------------------------------------
// K1b: combine K-half partials -> relu -> actH/actL [b][h] + actT [h][b] +
// actsum partials (r19-verbatim). grid = 64 x 256.
// ---------------------------------------------------------------------------
__global__ __launch_bounds__(256) void k_actc(
    const float* __restrict__ act_part,
    unsigned short* __restrict__ actH, unsigned short* __restrict__ actL,
    unsigned short* __restrict__ actT, float* __restrict__ actsum_part) {
  const int tid = threadIdx.x;
  const int blk = blockIdx.x;              // 0..63
  const int b0 = blk * 256;

  __shared__ unsigned short asT[32][264];
  __shared__ float red[256][4];

  const float4* p0 = (const float4*)act_part;
  const float4* p1 = p0 + (size_t)BATCH * HID / 4;

  const int hq = tid & 7;
  float4 s{0.f, 0.f, 0.f, 0.f};
#pragma unroll
  for (int r = 0; r < 8; ++r) {
    const int e4 = r * 256 + tid;
    const int b = e4 >> 3;
    const size_t g = (size_t)(b0 + b) * 8 + hq;
    float4 a = p0[g];
    float4 c = p1[g];
    a.x = fmaxf(a.x + c.x, 0.f);  a.y = fmaxf(a.y + c.y, 0.f);
    a.z = fmaxf(a.z + c.z, 0.f);  a.w = fmaxf(a.w + c.w, 0.f);
    ushort4 hh, ll;
    split2(a.x, hh.x, ll.x); split2(a.y, hh.y, ll.y);
    split2(a.z, hh.z, ll.z); split2(a.w, hh.w, ll.w);
    *(ushort4*)(&actH[g * 4]) = hh;
    *(ushort4*)(&actL[g * 4]) = ll;
    asT[hq * 4 + 0][b] = hh.x;
    asT[hq * 4 + 1][b] = hh.y;
    asT[hq * 4 + 2][b] = hh.z;
    asT[hq * 4 + 3][b] = hh.w;
    s.x += a.x; s.y += a.y; s.z += a.z; s.w += a.w;
  }
  red[tid][0] = s.x; red[tid][1] = s.y;
  red[tid][2] = s.z; red[tid][3] = s.w;
  __syncthreads();

#pragma unroll
  for (int r = 0; r < 4; ++r) {
    const int slot = r * 256 + tid;
    const int hrow = slot >> 5;
    const int bseg = (slot & 31) * 8;
    bf16x8 v = *(const bf16x8*)(&asT[hrow][bseg]);
    *(bf16x8*)(&actT[(size_t)hrow * BATCH + b0 + bseg]) = v;
  }
  if (tid < 32) {
    const int q = tid >> 2, j = tid & 3;
    float t = 0.f;
#pragma unroll
    for (int sx = 0; sx < 32; ++sx) t += red[q + 8 * sx][j];
    actsum_part[blk * HID + tid] = t;
  }
}

// ---------------------------------------------------------------------------
// K1c: corr1T_part = x^T @ act (+ xsum via ones tile). NOW READS xH bf16
// (written by k_act): half the x VMEM, zero conversions in staging.
// grid = 512 = (bc 0..127 x 128 b) x (iq 0..3), 512 thr, (512,4).
// ---------------------------------------------------------------------------
__global__ __launch_bounds__(512, 4) void k_corr1(
    const unsigned short* __restrict__ xH,
    const unsigned short* __restrict__ actT,
    float* __restrict__ corr1T_part, float* __restrict__ xsum_part) {
  const int tid = threadIdx.x;
  const int bc = blockIdx.x >> 2;          // 0..127
  const int iq = blockIdx.x & 3;           // 0..3
  const int b0 = bc * 128;
  const int ibase = iq * 512;
  const int lane = tid & 63;
  const int wv = tid >> 6;                 // 0..7
  const int arow = lane & 15;
  const int m4 = lane >> 4;
  const int ksub = m4 * 8;
  const int it = wv * 16;

  __shared__ __align__(16) unsigned short XT[128 * SXT];
  __shared__ __align__(16) unsigned short AT[48 * SATW];

  for (int e = tid; e < 16 * SATW; e += 512)
    AT[32 * SATW + e] = (unsigned short)0x3F80;
  if (tid < 256) {
    const int hrow = tid >> 3;             // 0..31
    const int bq16 = (tid & 7) * 16;       // 0..112
    const int sw = ((hrow >> 3) & 7) * 8;
#pragma unroll
    for (int j = 0; j < 2; ++j) {
      const int boff = bq16 + 8 * j;
      bf16x8 v = *(const bf16x8*)(&actT[(size_t)hrow * BATCH + b0 + boff]);
      *(bf16x8*)(&AT[hrow * SATW + (boff ^ sw)]) = v;
    }
  }

  const int ig = tid & 15;                 // i-group (8 i)
  const int bq = tid >> 4;                 // 0..31 -> half-local rows 2bq,2bq+1

  bf16x8 xa, ya;

#define LOADC(IC, HF)                                                       \
  {                                                                         \
    const int icol = ibase + (IC) * 128 + ig * 8;                           \
    const unsigned short* r0 =                                              \
        xH + (size_t)(b0 + 64 * (HF) + 2 * bq) * IND + icol;                \
    xa = *(const bf16x8*)(r0);                                              \
    ya = *(const bf16x8*)(r0 + IND);                                        \
  }

#define STC                                                                 \
  {                                                                         \
    const int qb = (2 * bq) ^ ((ig & 7) * 8);                               \
    unsigned short* basew = &XT[(size_t)(ig * 8) * SXT + qb];               \
    ushort2 p;                                                              \
    p.x = (unsigned short)xa[0]; p.y = (unsigned short)ya[0];               \
    *(ushort2*)(basew + 0 * SXT) = p;                                       \
    p.x = (unsigned short)xa[1]; p.y = (unsigned short)ya[1];               \
    *(ushort2*)(basew + 1 * SXT) = p;                                       \
    p.x = (unsigned short)xa[2]; p.y = (unsigned short)ya[2];               \
    *(ushort2*)(basew + 2 * SXT) = p;                                       \
    p.x = (unsigned short)xa[3]; p.y = (unsigned short)ya[3];               \
    *(ushort2*)(basew + 3 * SXT) = p;                                       \
    p.x = (unsigned short)xa[4]; p.y = (unsigned short)ya[4];               \
    *(ushort2*)(basew + 4 * SXT) = p;                                       \
    p.x = (unsigned short)xa[5]; p.y = (unsigned short)ya[5];               \
    *(ushort2*)(basew + 5 * SXT) = p;                                       \
    p.x = (unsigned short)xa[6]; p.y = (unsigned short)ya[6];               \
    *(ushort2*)(basew + 6 * SXT) = p;                                       \
    p.x = (unsigned short)xa[7]; p.y = (unsigned short)ya[7];               \
    *(ushort2*)(basew + 7 * SXT) = p;                                       \
  }

  const int swzr = (((it + arow) >> 3) & 7) * 8;
  const int swze0 = ((arow >> 3) & 7) * 8;
  const int swze1 = (((16 + arow) >> 3) & 7) * 8;

  LOADC(0, 0);
  for (int ic = 0; ic < 4; ++ic) {
    f32x4 c00 = {0.f, 0.f, 0.f, 0.f};
    f32x4 c01 = {0.f, 0.f, 0.f, 0.f};
    f32x4 c02 = {0.f, 0.f, 0.f, 0.f};
#pragma unroll
    for (int hf = 0; hf < 2; ++hf) {
      __syncthreads();                     // prev XT readers done (+AT w0)
      STC;
      __syncthreads();
      if (!(ic == 3 && hf == 1)) {
        const int nic = (hf == 1) ? ic + 1 : ic;
        const int nhf = hf ^ 1;
        LOADC(nic, nhf);
      }
#pragma unroll
      for (int bs = 0; bs < 2; ++bs) {
        const int bb = bs * 32 + ksub;     // within-64
        const int bb2 = 64 * hf + bb;      // within-128 (AT index)
        bf16x8 a = *(const bf16x8*)(&XT[(it + arow) * SXT + (bb ^ swzr)]);
        bf16x8 e0 = *(const bf16x8*)(&AT[arow * SATW + (bb2 ^ swze0)]);
        bf16x8 e1 = *(const bf16x8*)(&AT[(16 + arow) * SATW + (bb2 ^ swze1)]);
        bf16x8 e2 = *(const bf16x8*)(&AT[(32 + arow) * SATW + bb2]);
        c00 = __builtin_amdgcn_mfma_f32_16x16x32_bf16(a, e0, c00, 0, 0, 0);
        c01 = __builtin_amdgcn_mfma_f32_16x16x32_bf16(a, e1, c01, 0, 0, 0);
        c02 = __builtin_amdgcn_mfma_f32_16x16x32_bf16(a, e2, c02, 0, 0, 0);
      }
    }
    float* basep = corr1T_part + (size_t)bc * (IND * HID);
    const int gi = ibase + ic * 128 + it + (m4 << 2);
    *(f32x4*)(basep + (size_t)arow * IND + gi) = c00;
    *(f32x4*)(basep + (size_t)(16 + arow) * IND + gi) = c01;
    if (arow == 0)
      *(f32x4*)(xsum_part + (size_t)bc * IND + gi) = c02;
  }
}

// ---------------------------------------------------------------------------
// K1d: deterministic reduce (corr1T/xsum: 128 slices, actsum: 64).
// ---------------------------------------------------------------------------
__global__ __launch_bounds__(256) void k_red1(
    const float* __restrict__ c1p, const float* __restrict__ xsp,
    const float* __restrict__ asp,
    float* __restrict__ corr1T, float* __restrict__ xsum,
    float* __restrict__ actsum) {
  const int e = blockIdx.x * 256 + threadIdx.x;
  float s = 0.f;
#pragma unroll 8
  for (int c = 0; c < NC1; ++c) s += c1p[(size_t)c * (IND * HID) + e];
  corr1T[e] = s;
  if (e < IND) {
    float t = 0.f;
#pragma unroll 8
    for (int c = 0; c < NC1; ++c) t += xsp[(size_t)c * IND + e];
    xsum[e] = t;
  }
  if (e < HID) {
    float t = 0.f;
#pragma unroll 8
    for (int c = 0; c < NSA; ++c) t += asp[(size_t)c * HID + e];
    actsum[e] = t;
  }
}

// ---------------------------------------------------------------------------
// K3: layer-2 MFMA. Now 128-b blocks (two 64-b halves), corr2/outsum
// accumulated in C-regs across halves -> NC2 256->128 (halves partial
// traffic). grid = 512 = (bc 0..127) x (og 0..3); 256 thr, 62KB LDS.
// ---------------------------------------------------------------------------
__global__ __launch_bounds__(256, 2) void k_fwd2m(
    const unsigned short* __restrict__ actH,
    const unsigned short* __restrict__ actL,
    const unsigned short* __restrict__ actT,
    const unsigned short* __restrict__ w2H,
    const unsigned short* __restrict__ w2L,
    float* __restrict__ out, float* __restrict__ corr2_part,
    float* __restrict__ outsum_part) {
  const int tid = threadIdx.x;
  const int bc = blockIdx.x >> 2;          // 0..127
  const int og = blockIdx.x & 3;           // 0..3
  const int b0 = bc * 128;
  const int obase = og * 128;
  const int lane = tid & 63;
  const int wv = tid >> 6;                 // 0..3
  const int arow = lane & 15;
  const int m4 = lane >> 4;
  const int ksub = m4 * 8;

  __shared__ __align__(16) unsigned short W2Hs[128 * 40];
  __shared__ __align__(16) unsigned short W2Ls[128 * 40];
  __shared__ __align__(16) unsigned short AH[64 * 40];
  __shared__ __align__(16) unsigned short AL[64 * 40];
  __shared__ __align__(16) unsigned short AT[48 * SATW];
  __shared__ __align__(16) unsigned short OT[128 * 72];

  {  // stage w2 hi/lo once
    const int r2 = tid >> 1, hh = (tid & 1) * 16;
    const size_t wo = (size_t)(obase + r2) * HID + hh;
    *(bf16x8*)(&W2Hs[r2 * 40 + hh]) = *(const bf16x8*)(&w2H[wo]);
    *(bf16x8*)(&W2Hs[r2 * 40 + hh + 8]) = *(const bf16x8*)(&w2H[wo + 8]);
    *(bf16x8*)(&W2Ls[r2 * 40 + hh]) = *(const bf16x8*)(&w2L[wo]);
    *(bf16x8*)(&W2Ls[r2 * 40 + hh + 8]) = *(const bf16x8*)(&w2L[wo + 8]);
  }
  {  // stage actT [32 h][128 b] once + ones rows 32..47
    const int h = tid >> 3, seg16 = (tid & 7) * 16;
#pragma unroll
    for (int j = 0; j < 2; ++j) {
      const int seg = seg16 + 8 * j;
      *(bf16x8*)(&AT[h * SATW + seg]) =
          *(const bf16x8*)(&actT[(size_t)h * BATCH + b0 + seg]);
    }
  }
  for (int e = tid; e < 16 * SATW; e += 256)
    AT[32 * SATW + e] = (unsigned short)0x3F80;

  f32x4 c0a = {0.f,0.f,0.f,0.f}, c1a = {0.f,0.f,0.f,0.f}, c2a = {0.f,0.f,0.f,0.f};
  f32x4 c0b = {0.f,0.f,0.f,0.f}, c1b = {0.f,0.f,0.f,0.f}, c2b = {0.f,0.f,0.f,0.f};

  for (int hf = 0; hf < 2; ++hf) {
    __syncthreads();                       // prior readers of AH/OT done
    {  // stage act hi/lo [64 b][32 h] for this half
      const int b = tid >> 2, q = (tid & 3) * 8;
      *(bf16x8*)(&AH[b * 40 + q]) =
          *(const bf16x8*)(&actH[(size_t)(b0 + 64 * hf + b) * HID + q]);
      *(bf16x8*)(&AL[b * 40 + q]) =
          *(const bf16x8*)(&actL[(size_t)(b0 + 64 * hf + b) * HID + q]);
    }
    __syncthreads();

    // forward: wave = b-tile within half
    const int bt = wv;
    bf16x8 fah = *(const bf16x8*)(&AH[(bt * 16 + arow) * 40 + ksub]);
    bf16x8 fal = *(const bf16x8*)(&AL[(bt * 16 + arow) * 40 + ksub]);
#pragma unroll
    for (int ot = 0; ot < 8; ++ot) {
      bf16x8 wbh = *(const bf16x8*)(&W2Hs[(ot * 16 + arow) * 40 + ksub]);
      bf16x8 wbl = *(const bf16x8*)(&W2Ls[(ot * 16 + arow) * 40 + ksub]);
      f32x4 z = {0.f, 0.f, 0.f, 0.f};
      z = __builtin_amdgcn_mfma_f32_16x16x32_bf16(fah, wbh, z, 0, 0, 0);
      z = __builtin_amdgcn_mfma_f32_16x16x32_bf16(fah, wbl, z, 0, 0, 0);
      z = __builtin_amdgcn_mfma_f32_16x16x32_bf16(fal, wbh, z, 0, 0, 0);
      ushort4 po;
      {
        float ov0 = 1.0f / (1.0f + __expf(-z[0])) - 0.4f;
        float ov1 = 1.0f / (1.0f + __expf(-z[1])) - 0.4f;
        float ov2 = 1.0f / (1.0f + __expf(-z[2])) - 0.4f;
        float ov3 = 1.0f / (1.0f + __expf(-z[3])) - 0.4f;
        const size_t ob = (size_t)(b0 + 64 * hf + bt * 16 + m4 * 4) * OUTD +
                          obase + ot * 16 + arow;
        out[ob + 0 * OUTD] = ov0;
        out[ob + 1 * OUTD] = ov1;
        out[ob + 2 * OUTD] = ov2;
        out[ob + 3 * OUTD] = ov3;
        po.x = f2bf(ov0); po.y = f2bf(ov1); po.z = f2bf(ov2); po.w = f2bf(ov3);
      }
      *(ushort4*)(&OT[(ot * 16 + arow) * 72 + bt * 16 + m4 * 4]) = po;
    }
    __syncthreads();

    // corr2 + outsum accumulate (ot = 2wv, 2wv+1), AT cols at 64*hf
    {
      const int ot = wv * 2;
#pragma unroll
      for (int ks = 0; ks < 2; ++ks) {
        const int bb = ks * 32 + ksub;
        const int bb2 = 64 * hf + bb;
        bf16x8 bo = *(const bf16x8*)(&OT[(ot * 16 + arow) * 72 + bb]);
        bf16x8 a0 = *(const bf16x8*)(&AT[arow * SATW + bb2]);
        bf16x8 a1 = *(const bf16x8*)(&AT[(16 + arow) * SATW + bb2]);
        bf16x8 a2 = *(const bf16x8*)(&AT[(32 + arow) * SATW + bb2]);
        c0a = __builtin_amdgcn_mfma_f32_16x16x32_bf16(a0, bo, c0a, 0, 0, 0);
        c1a = __builtin_amdgcn_mfma_f32_16x16x32_bf16(a1, bo, c1a, 0, 0, 0);
        c2a = __builtin_amdgcn_mfma_f32_16x16x32_bf16(a2, bo, c2a, 0, 0, 0);
      }
    }
    {
      const int ot = wv * 2 + 1;
#pragma unroll
      for (int ks = 0; ks < 2; ++ks) {
        const int bb = ks * 32 + ksub;
        const int bb2 = 64 * hf + bb;
        bf16x8 bo = *(const bf16x8*)(&OT[(ot * 16 + arow) * 72 + bb]);
        bf16x8 a0 = *(const bf16x8*)(&AT[arow * SATW + bb2]);
        bf16x8 a1 = *(const bf16x8*)(&AT[(16 + arow) * SATW + bb2]);
        bf16x8 a2 = *(const bf16x8*)(&AT[(32 + arow) * SATW + bb2]);
        c0b = __builtin_amdgcn_mfma_f32_16x16x32_bf16(a0, bo, c0b, 0, 0, 0);
        c1b = __builtin_amdgcn_mfma_f32_16x16x32_bf16(a1, bo, c1b, 0, 0, 0);
        c2b = __builtin_amdgcn_mfma_f32_16x16x32_bf16(a2, bo, c2b, 0, 0, 0);
      }
    }
  }

  {  // write corr2_part / outsum_part (bc in 0..127)
    const int ot0 = wv * 2, ot1 = wv * 2 + 1;
    float* cp0 = corr2_part + (size_t)bc * (HID * OUTD) + obase + ot0 * 16 + arow;
    float* cp1 = corr2_part + (size_t)bc * (HID * OUTD) + obase + ot1 * 16 + arow;
#pragma unroll
    for (int r = 0; r < 4; ++r) {
      cp0[(size_t)(m4 * 4 + r) * OUTD] = c0a[r];
      cp0[(size_t)(16 + m4 * 4 + r) * OUTD] = c1a[r];
      cp1[(size_t)(m4 * 4 + r) * OUTD] = c0b[r];
      cp1[(size_t)(16 + m4 * 4 + r) * OUTD] = c1b[r];
    }
    if (m4 == 0) {
      outsum_part[(size_t)bc * OUTD + obase + ot0 * 16 + arow] = c2a[0];
      outsum_part[(size_t)bc * OUTD + obase + ot1 * 16 + arow] = c2b[0];
    }
  }
}

// ---------------------------------------------------------------------------
// K3b: deterministic reduce of corr2/outsum partials (128 slices).
// ---------------------------------------------------------------------------
__global__ __launch_bounds__(256) void k_red2(
    const float* __restrict__ corr2_part, const float* __restrict__ outsum_part,
    float* __restrict__ corr2, float* __restrict__ outsum) {
  const int e = blockIdx.x * 256 + threadIdx.x;
  float s = 0.f;
#pragma unroll 8
  for (int c = 0; c < NC2; ++c) s += corr2_part[(size_t)c * (HID * OUTD) + e];
  corr2[e] = s;
  if (e < OUTD) {
    float t = 0.f;
#pragma unroll 8
    for (int c = 0; c < NC2; ++c) t += outsum_part[(size_t)c * OUTD + e];
    outsum[e] = t;
  }
}

// ---------------------------------------------------------------------------
// K4: w1_new[h,i] = (w1[h,i] + dw1T[i,h]) / ||row h||_2 ; corr1T[h][i].
// ---------------------------------------------------------------------------
__global__ __launch_bounds__(256) void k_w1(
    const float* __restrict__ w1, const float* __restrict__ heb,
    const float* __restrict__ corr1T, const float* __restrict__ xsum,
    const float* __restrict__ actsum, float* __restrict__ w1out) {
  const int h = blockIdx.x;
  const int tid = threadIdx.x;
  const float ash = actsum[h];
  const float4* heb4 = (const float4*)heb;

  float val[8];
  float ss = 0.f;
#pragma unroll
  for (int r = 0; r < 8; ++r) {
    const int i = tid + 256 * r;
    float4 c = heb4[(size_t)i * HID + h];
    float v = w1[(size_t)h * IND + i] + 16384.0f * c.w +
              c.x * corr1T[(size_t)h * IND + i] + c.y * xsum[i] + c.z * ash;
    val[r] = v;
    ss += v * v;
  }

  __shared__ float red[256];
  red[tid] = ss;
  __syncthreads();
  for (int s = 128; s > 0; s >>= 1) {
    if (tid < s) red[tid] += red[tid + s];
    __syncthreads();
  }
  const float inv = 1.0f / sqrtf(red[0]);
#pragma unroll
  for (int r = 0; r < 8; ++r) {
    const int i = tid + 256 * r;
    w1out[(size_t)h * IND + i] = val[r] * inv;
  }
}

// ---------------------------------------------------------------------------
// K5: w2_new[o,h] = (w2[o,h] + dw2T[h,o]) / ||row o||_2
// ---------------------------------------------------------------------------
__global__ __launch_bounds__(256) void k_w2(
    const float* __restrict__ w2, const float* __restrict__ heb,
    const float* __restrict__ corr2, const float* __restrict__ actsum,
    const float* __restrict__ outsum, float* __restrict__ w2out) {
  const int o = blockIdx.x * 256 + threadIdx.x;
  const float oso = outsum[o];
  const float4* heb4 = (const float4*)heb;

  float val[HID];
  float ss = 0.f;
#pragma unroll
  for (int h = 0; h < HID; ++h) {
    float4 c = heb4[(size_t)(HID * IND) + (size_t)h * OUTD + o];
    float v = w2[(size_t)o * HID + h] + 16384.0f * c.w +
              c.x * corr2[(size_t)h * OUTD + o] + c.y * actsum[h] + c.z * oso;
    val[h] = v;
    ss += v * v;
  }
  const float inv = 1.0f / sqrtf(ss);
#pragma unroll
  for (int h = 0; h < HID; ++h) w2out[(size_t)o * HID + h] = val[h] * inv;
}

// ---------------------------------------------------------------------------
extern "C" void kernel_launch(void* const* d_in, const int* in_sizes, int n_in,
                              void* d_out, int out_size, void* d_ws,
                              size_t ws_size, hipStream_t stream) {
  const float* x   = (const float*)d_in[0];   // [16384, 2048]
  const float* w1  = (const float*)d_in[1];   // [32, 2048]
  const float* w2  = (const float*)d_in[2];   // [512, 32]
  const float* heb = (const float*)d_in[3];   // [81920, 4]

  float* out = (float*)d_out;                 // [16384, 512]
  float* w1o = out + (size_t)BATCH * OUTD;    // [32, 2048]
  float* w2o = w1o + (size_t)HID * IND;       // [512, 32]

  float* ws = (float*)d_ws;                   // ws ~537 MB; layout ~125 MB
  unsigned short* actH = (unsigned short*)ws;                      // 262144 f
  unsigned short* actL = actH + (size_t)BATCH * HID;               // 262144 f
  unsigned short* actT = actL + (size_t)BATCH * HID;               // 262144 f
  unsigned short* w1H  = actT + (size_t)BATCH * HID;               // 32768 f
  unsigned short* w1L  = w1H + (size_t)HID * IND;                  // 32768 f
  unsigned short* w2H  = w1L + (size_t)HID * IND;                  // 8192 f
  unsigned short* w2L  = w2H + (size_t)OUTD * HID;                 // 8192 f
  unsigned short* xH   = w2L + (size_t)OUTD * HID;                 // 16.8M f
  float* corr1T      = (float*)(xH + (size_t)BATCH * IND);         // 65536
  float* corr2       = corr1T + (size_t)IND * HID;                 // 16384
  float* xsum        = corr2 + (size_t)HID * OUTD;                 // 2048
  float* actsum      = xsum + IND;                                 // 32
  float* outsum      = actsum + HID;                               // 512
  float* act_part    = outsum + OUTD;                              // 2*524288
  float* corr1T_part = act_part + (size_t)2 * BATCH * HID;         // 128*65536
  float* xsum_part   = corr1T_part + (size_t)NC1 * IND * HID;      // 128*2048
  float* actsum_part = xsum_part + (size_t)NC1 * IND;              // 64*32
  float* corr2_part  = actsum_part + (size_t)NSA * HID;            // 128*16384
  float* outsum_part = corr2_part + (size_t)NC2 * HID * OUTD;      // 128*512

  k_cvtw <<<80, 256, 0, stream>>>(w1, w2, w1H, w1L, w2H, w2L);
  k_act  <<<1024, 256, 0, stream>>>(x, w1H, w1L, act_part, xH);
  k_actc <<<64, 256, 0, stream>>>(act_part, actH, actL, actT, actsum_part);
  k_corr1<<<512, 512, 0, stream>>>(xH, actT, corr1T_part, xsum_part);
  k_red1 <<<256, 256, 0, stream>>>(corr1T_part, xsum_part, actsum_part,
                                   corr1T, xsum, actsum);
  k_fwd2m<<<512, 256, 0, stream>>>(actH, actL, actT, w2H, w2L, out,
                                   corr2_part, outsum_part);
  k_red2 <<<64, 256, 0, stream>>>(corr2_part, outsum_part, corr2, outsum);
  k_w1   <<<32, 256, 0, stream>>>(w1, heb, corr1T, xsum, actsum, w1o);
  k_w2   <<<2, 256, 0, stream>>>(w2, heb, corr2, actsum, outsum, w2o);
}

// Round 21
// 116.814 us; speedup vs baseline: 1.3805x; 1.0920x over previous
//
#include <hip/hip_runtime.h>
#include <math.h>

// Problem constants
constexpr int BATCH = 16384;
constexpr int IND   = 2048;   // INPUT
constexpr int HID   = 32;     // HIDDEN
constexpr int OUTD  = 512;    // OUTPUT

constexpr int NC1 = 64;       // corr1/xsum partial slices (b-chunks of 256)
constexpr int NSA = 64;       // actsum partial slices (k_actc blocks)
constexpr int NC2 = 128;      // corr2/outsum partial slices (b-chunks of 128)

constexpr int SA   = 136;     // ushort row stride, k_act tiles
constexpr int SXT  = 72;      // ushort row stride, k_corr1 xT tile (64 b)
constexpr int SATW = 136;     // ushort row stride, k_fwd2m actT tile (128 b)
constexpr int SAT2 = 264;     // ushort row stride, k_corr1 actT tile (256 b)

typedef __attribute__((ext_vector_type(8))) short bf16x8;
typedef __attribute__((ext_vector_type(4))) float f32x4;

__device__ __forceinline__ unsigned short f2bf(float f) {
  unsigned u = __float_as_uint(f);
  u += 0x7FFFu + ((u >> 16) & 1u);          // round-to-nearest-even
  return (unsigned short)(u >> 16);
}
__device__ __forceinline__ float bf2f(unsigned short h) {
  return __uint_as_float(((unsigned)h) << 16);
}
__device__ __forceinline__ void split2(float f, unsigned short& hi,
                                       unsigned short& lo) {
  hi = f2bf(f);
  lo = f2bf(f - bf2f(hi));
}
__device__ __forceinline__ int swzA(int row, int col) {
  return row * SA + (col ^ (((row >> 3) & 7) * 8));
}

// ---------------------------------------------------------------------------
// K0: pre-split w1/w2 to hi/lo bf16 once (r19-verified).
// ---------------------------------------------------------------------------
__global__ __launch_bounds__(256) void k_cvtw(
    const float* __restrict__ w1, const float* __restrict__ w2,
    unsigned short* __restrict__ w1H, unsigned short* __restrict__ w1L,
    unsigned short* __restrict__ w2H, unsigned short* __restrict__ w2L) {
  const int bid = blockIdx.x;
  if (bid < 64) {
    const int g = bid * 256 + threadIdx.x;          // < 16384
    float4 v = ((const float4*)w1)[g];
    ushort4 h, l;
    split2(v.x, h.x, l.x); split2(v.y, h.y, l.y);
    split2(v.z, h.z, l.z); split2(v.w, h.w, l.w);
    ((ushort4*)w1H)[g] = h;
    ((ushort4*)w1L)[g] = l;
  } else {
    const int g = (bid - 64) * 256 + threadIdx.x;   // < 4096
    float4 v = ((const float4*)w2)[g];
    ushort4 h, l;
    split2(v.x, h.x, l.x); split2(v.y, h.y, l.y);
    split2(v.z, h.z, l.z); split2(v.w, h.w, l.w);
    ((ushort4*)w2H)[g] = h;
    ((ushort4*)w2L)[g] = l;
  }
}

// ---------------------------------------------------------------------------
// K1a: act partials = x @ w1T, split-bf16 MFMA; also emits xH bf16 [b][k]
// (r20-verified). grid = 1024 = (bt x 32 rows) x kq; (256,4).
// ---------------------------------------------------------------------------
__global__ __launch_bounds__(256, 4) void k_act(
    const float* __restrict__ x, const unsigned short* __restrict__ w1H,
    const unsigned short* __restrict__ w1L, float* __restrict__ act_part,
    unsigned short* __restrict__ xH) {
  const int tid = threadIdx.x;
  const int kq = blockIdx.x & 1;
  const int bt = blockIdx.x >> 1;          // 0..511
  const int b0 = bt * 32;
  const int kbase = kq * 1024;
  const int lane = tid & 63;
  const int wv = tid >> 6;                 // 0..3
  const int arow = lane & 15;
  const int m4 = lane >> 4;                // 0..3
  const int ksub = m4 * 8;
  const int rt = wv & 1;
  const int ht = wv >> 1;

  __shared__ __align__(16) unsigned short XH[32 * SA];
  __shared__ __align__(16) unsigned short XL[32 * SA];
  __shared__ __align__(16) unsigned short WH[32 * SA];
  __shared__ __align__(16) unsigned short WL[32 * SA];

  const int rp = tid >> 4;
  const int kg = (tid & 15) * 8;

  float4 px0a, px0b, px1a, px1b;
  bf16x8 pwh0, pwl0, pwh1, pwl1;

#define LOADA(K0)                                                          \
  {                                                                        \
    const float* xr0 = x + (size_t)(b0 + 2 * rp) * IND + kbase + (K0) + kg;\
    const float* xr1 = xr0 + IND;                                          \
    px0a = *(const float4*)(xr0);                                          \
    px0b = *(const float4*)(xr0 + 4);                                      \
    px1a = *(const float4*)(xr1);                                          \
    px1b = *(const float4*)(xr1 + 4);                                      \
    const size_t wo = (size_t)(2 * rp) * IND + kbase + (K0) + kg;          \
    pwh0 = *(const bf16x8*)(&w1H[wo]);                                     \
    pwl0 = *(const bf16x8*)(&w1L[wo]);                                     \
    pwh1 = *(const bf16x8*)(&w1H[wo + IND]);                               \
    pwl1 = *(const bf16x8*)(&w1L[wo + IND]);                               \
  }

#define PUTX2(ROW, COL, V, GK)                                       \
  {                                                                  \
    ushort4 h_, l_;                                                  \
    split2((V).x, h_.x, l_.x); split2((V).y, h_.y, l_.y);            \
    split2((V).z, h_.z, l_.z); split2((V).w, h_.w, l_.w);            \
    *(ushort4*)(&XH[swzA((ROW), (COL))]) = h_;                       \
    *(ushort4*)(&XL[swzA((ROW), (COL))]) = l_;                       \
    *(ushort4*)(&xH[(size_t)(b0 + (ROW)) * IND + (GK) + (COL)]) = h_;\
  }

#define STOREA(GK)                                                   \
  {                                                                  \
    PUTX2(2 * rp, kg, px0a, GK);                                     \
    PUTX2(2 * rp, kg + 4, px0b, GK);                                 \
    PUTX2(2 * rp + 1, kg, px1a, GK);                                 \
    PUTX2(2 * rp + 1, kg + 4, px1b, GK);                             \
    *(bf16x8*)(&WH[swzA(2 * rp, kg)]) = pwh0;                        \
    *(bf16x8*)(&WL[swzA(2 * rp, kg)]) = pwl0;                        \
    *(bf16x8*)(&WH[swzA(2 * rp + 1, kg)]) = pwh1;                    \
    *(bf16x8*)(&WL[swzA(2 * rp + 1, kg)]) = pwl1;                    \
  }

  f32x4 accA = {0.f, 0.f, 0.f, 0.f};
  LOADA(0);

  for (int kc = 0; kc < 8; ++kc) {
    __syncthreads();
    STOREA(kbase + kc * 128);
    __syncthreads();
    if (kc < 7) LOADA((kc + 1) * 128);
    const int xrow = rt * 16 + arow;
    const int wrow = ht * 16 + arow;
#pragma unroll
    for (int ks = 0; ks < 4; ++ks) {
      const int kk = ks * 32 + ksub;
      bf16x8 ah = *(const bf16x8*)(&XH[swzA(xrow, kk)]);
      bf16x8 al = *(const bf16x8*)(&XL[swzA(xrow, kk)]);
      bf16x8 bh = *(const bf16x8*)(&WH[swzA(wrow, kk)]);
      bf16x8 bl_ = *(const bf16x8*)(&WL[swzA(wrow, kk)]);
      accA = __builtin_amdgcn_mfma_f32_16x16x32_bf16(ah, bh, accA, 0, 0, 0);
      accA = __builtin_amdgcn_mfma_f32_16x16x32_bf16(ah, bl_, accA, 0, 0, 0);
      accA = __builtin_amdgcn_mfma_f32_16x16x32_bf16(al, bh, accA, 0, 0, 0);
    }
  }

  const int bl = rt * 16 + (m4 << 2);
  const int h = ht * 16 + arow;
  float* p = act_part + (size_t)kq * (BATCH * HID);
#pragma unroll
  for (int r = 0; r < 4; ++r)
    p[(size_t)(b0 + bl + r) * HID + h] = accA[r];
}

// ---------------------------------------------------------------------------
// K1b: combine K-half partials -> relu -> actH/actL [b][h] + actT [h][b] +
// actsum partials (r19-verbatim). grid = 64 x 256.
// ---------------------------------------------------------------------------
__global__ __launch_bounds__(256) void k_actc(
    const float* __restrict__ act_part,
    unsigned short* __restrict__ actH, unsigned short* __restrict__ actL,
    unsigned short* __restrict__ actT, float* __restrict__ actsum_part) {
  const int tid = threadIdx.x;
  const int blk = blockIdx.x;              // 0..63
  const int b0 = blk * 256;

  __shared__ unsigned short asT[32][264];
  __shared__ float red[256][4];

  const float4* p0 = (const float4*)act_part;
  const float4* p1 = p0 + (size_t)BATCH * HID / 4;

  const int hq = tid & 7;
  float4 s{0.f, 0.f, 0.f, 0.f};
#pragma unroll
  for (int r = 0; r < 8; ++r) {
    const int e4 = r * 256 + tid;
    const int b = e4 >> 3;
    const size_t g = (size_t)(b0 + b) * 8 + hq;
    float4 a = p0[g];
    float4 c = p1[g];
    a.x = fmaxf(a.x + c.x, 0.f);  a.y = fmaxf(a.y + c.y, 0.f);
    a.z = fmaxf(a.z + c.z, 0.f);  a.w = fmaxf(a.w + c.w, 0.f);
    ushort4 hh, ll;
    split2(a.x, hh.x, ll.x); split2(a.y, hh.y, ll.y);
    split2(a.z, hh.z, ll.z); split2(a.w, hh.w, ll.w);
    *(ushort4*)(&actH[g * 4]) = hh;
    *(ushort4*)(&actL[g * 4]) = ll;
    asT[hq * 4 + 0][b] = hh.x;
    asT[hq * 4 + 1][b] = hh.y;
    asT[hq * 4 + 2][b] = hh.z;
    asT[hq * 4 + 3][b] = hh.w;
    s.x += a.x; s.y += a.y; s.z += a.z; s.w += a.w;
  }
  red[tid][0] = s.x; red[tid][1] = s.y;
  red[tid][2] = s.z; red[tid][3] = s.w;
  __syncthreads();

#pragma unroll
  for (int r = 0; r < 4; ++r) {
    const int slot = r * 256 + tid;
    const int hrow = slot >> 5;
    const int bseg = (slot & 31) * 8;
    bf16x8 v = *(const bf16x8*)(&asT[hrow][bseg]);
    *(bf16x8*)(&actT[(size_t)hrow * BATCH + b0 + bseg]) = v;
  }
  if (tid < 32) {
    const int q = tid >> 2, j = tid & 3;
    float t = 0.f;
#pragma unroll
    for (int sx = 0; sx < 32; ++sx) t += red[q + 8 * sx][j];
    actsum_part[blk * HID + tid] = t;
  }
}

// ---------------------------------------------------------------------------
// K1c: corr1T_part = x^T @ act (+ xsum via ones tile), reading xH bf16.
// NOW 256-b chunks: each block accumulates FOUR 64-b halves in C-regs ->
// NC1 128->64 (partial round-trip 33.5->16.8 MB each way).
// grid = 1024 = (bc 0..63 b-chunks of 256) x (iq 0..15 i-quadrants of 128).
// 512 thr (8 waves; wave = 16-i tile). LDS 43.7KB -> (512,3) = 24 waves/CU.
// ---------------------------------------------------------------------------
__global__ __launch_bounds__(512, 3) void k_corr1(
    const unsigned short* __restrict__ xH,
    const unsigned short* __restrict__ actT,
    float* __restrict__ corr1T_part, float* __restrict__ xsum_part) {
  const int tid = threadIdx.x;
  const int bc = blockIdx.x >> 4;          // 0..63
  const int iq = blockIdx.x & 15;          // 0..15
  const int b0 = bc * 256;
  const int ibase = iq * 128;
  const int lane = tid & 63;
  const int wv = tid >> 6;                 // 0..7
  const int arow = lane & 15;
  const int m4 = lane >> 4;
  const int ksub = m4 * 8;
  const int it = wv * 16;                  // wave's i-tile base (0..112)

  __shared__ __align__(16) unsigned short XT[128 * SXT];   // [128 i][64 b]
  __shared__ __align__(16) unsigned short AT[48 * SAT2];   // [48][256 b]

  // ones rows 32..47
  for (int e = tid; e < 16 * SAT2; e += 512)
    AT[32 * SAT2 + e] = (unsigned short)0x3F80;
  // stage actT [32 h][256 b], swizzled per 8-granule: 512 thr x 2 seg
  {
    const int hrow = tid >> 4;             // 0..31
    const int sg = (tid & 15) * 16;        // 0..240
    const int sw = ((hrow >> 3) & 7) * 8;
#pragma unroll
    for (int j = 0; j < 2; ++j) {
      const int boff = sg + 8 * j;
      bf16x8 v = *(const bf16x8*)(&actT[(size_t)hrow * BATCH + b0 + boff]);
      *(bf16x8*)(&AT[hrow * SAT2 + (boff ^ sw)]) = v;
    }
  }

  const int ig = tid & 15;                 // i-group (8 i)
  const int bq = tid >> 4;                 // 0..31 -> half-local rows 2bq,2bq+1

  bf16x8 xa, ya;

#define LOADC(HF)                                                           \
  {                                                                         \
    const int icol = ibase + ig * 8;                                        \
    const unsigned short* r0 =                                              \
        xH + (size_t)(b0 + 64 * (HF) + 2 * bq) * IND + icol;                \
    xa = *(const bf16x8*)(r0);                                              \
    ya = *(const bf16x8*)(r0 + IND);                                        \
  }

#define STC                                                                 \
  {                                                                         \
    const int qb = (2 * bq) ^ ((ig & 7) * 8);                               \
    unsigned short* basew = &XT[(size_t)(ig * 8) * SXT + qb];               \
    ushort2 p;                                                              \
    p.x = (unsigned short)xa[0]; p.y = (unsigned short)ya[0];               \
    *(ushort2*)(basew + 0 * SXT) = p;                                       \
    p.x = (unsigned short)xa[1]; p.y = (unsigned short)ya[1];               \
    *(ushort2*)(basew + 1 * SXT) = p;                                       \
    p.x = (unsigned short)xa[2]; p.y = (unsigned short)ya[2];               \
    *(ushort2*)(basew + 2 * SXT) = p;                                       \
    p.x = (unsigned short)xa[3]; p.y = (unsigned short)ya[3];               \
    *(ushort2*)(basew + 3 * SXT) = p;                                       \
    p.x = (unsigned short)xa[4]; p.y = (unsigned short)ya[4];               \
    *(ushort2*)(basew + 4 * SXT) = p;                                       \
    p.x = (unsigned short)xa[5]; p.y = (unsigned short)ya[5];               \
    *(ushort2*)(basew + 5 * SXT) = p;                                       \
    p.x = (unsigned short)xa[6]; p.y = (unsigned short)ya[6];               \
    *(ushort2*)(basew + 6 * SXT) = p;                                       \
    p.x = (unsigned short)xa[7]; p.y = (unsigned short)ya[7];               \
    *(ushort2*)(basew + 7 * SXT) = p;                                       \
  }

  const int swzr = (((it + arow) >> 3) & 7) * 8;
  const int swze0 = ((arow >> 3) & 7) * 8;
  const int swze1 = (((16 + arow) >> 3) & 7) * 8;

  f32x4 c00 = {0.f, 0.f, 0.f, 0.f};
  f32x4 c01 = {0.f, 0.f, 0.f, 0.f};
  f32x4 c02 = {0.f, 0.f, 0.f, 0.f};

  LOADC(0);
#pragma unroll
  for (int hf = 0; hf < 4; ++hf) {
    __syncthreads();                       // prev XT readers done (+AT w0)
    STC;
    __syncthreads();
    if (hf < 3) LOADC(hf + 1);             // issue next half's loads EARLY
#pragma unroll
    for (int bs = 0; bs < 2; ++bs) {
      const int bb = bs * 32 + ksub;       // within-64
      const int bb2 = 64 * hf + bb;        // within-256 (AT index)
      bf16x8 a = *(const bf16x8*)(&XT[(it + arow) * SXT + (bb ^ swzr)]);
      bf16x8 e0 = *(const bf16x8*)(&AT[arow * SAT2 + (bb2 ^ swze0)]);
      bf16x8 e1 = *(const bf16x8*)(&AT[(16 + arow) * SAT2 + (bb2 ^ swze1)]);
      bf16x8 e2 = *(const bf16x8*)(&AT[(32 + arow) * SAT2 + bb2]);
      c00 = __builtin_amdgcn_mfma_f32_16x16x32_bf16(a, e0, c00, 0, 0, 0);
      c01 = __builtin_amdgcn_mfma_f32_16x16x32_bf16(a, e1, c01, 0, 0, 0);
      c02 = __builtin_amdgcn_mfma_f32_16x16x32_bf16(a, e2, c02, 0, 0, 0);
    }
  }

  float* basep = corr1T_part + (size_t)bc * (IND * HID);
  const int gi = ibase + it + (m4 << 2);
  *(f32x4*)(basep + (size_t)arow * IND + gi) = c00;
  *(f32x4*)(basep + (size_t)(16 + arow) * IND + gi) = c01;
  if (arow == 0)
    *(f32x4*)(xsum_part + (size_t)bc * IND + gi) = c02;
}

// ---------------------------------------------------------------------------
// K1d: deterministic reduce (corr1T/xsum: 64 slices, actsum: 64).
// ---------------------------------------------------------------------------
__global__ __launch_bounds__(256) void k_red1(
    const float* __restrict__ c1p, const float* __restrict__ xsp,
    const float* __restrict__ asp,
    float* __restrict__ corr1T, float* __restrict__ xsum,
    float* __restrict__ actsum) {
  const int e = blockIdx.x * 256 + threadIdx.x;
  float s = 0.f;
#pragma unroll 8
  for (int c = 0; c < NC1; ++c) s += c1p[(size_t)c * (IND * HID) + e];
  corr1T[e] = s;
  if (e < IND) {
    float t = 0.f;
#pragma unroll 8
    for (int c = 0; c < NC1; ++c) t += xsp[(size_t)c * IND + e];
    xsum[e] = t;
  }
  if (e < HID) {
    float t = 0.f;
#pragma unroll 8
    for (int c = 0; c < NSA; ++c) t += asp[(size_t)c * HID + e];
    actsum[e] = t;
  }
}

// ---------------------------------------------------------------------------
// K3: layer-2 MFMA, 128-b blocks, C-reg accumulation across halves
// (r20-verified). grid = 512 = (bc 0..127) x (og 0..3); 256 thr.
// ---------------------------------------------------------------------------
__global__ __launch_bounds__(256, 2) void k_fwd2m(
    const unsigned short* __restrict__ actH,
    const unsigned short* __restrict__ actL,
    const unsigned short* __restrict__ actT,
    const unsigned short* __restrict__ w2H,
    const unsigned short* __restrict__ w2L,
    float* __restrict__ out, float* __restrict__ corr2_part,
    float* __restrict__ outsum_part) {
  const int tid = threadIdx.x;
  const int bc = blockIdx.x >> 2;          // 0..127
  const int og = blockIdx.x & 3;           // 0..3
  const int b0 = bc * 128;
  const int obase = og * 128;
  const int lane = tid & 63;
  const int wv = tid >> 6;                 // 0..3
  const int arow = lane & 15;
  const int m4 = lane >> 4;
  const int ksub = m4 * 8;

  __shared__ __align__(16) unsigned short W2Hs[128 * 40];
  __shared__ __align__(16) unsigned short W2Ls[128 * 40];
  __shared__ __align__(16) unsigned short AH[64 * 40];
  __shared__ __align__(16) unsigned short AL[64 * 40];
  __shared__ __align__(16) unsigned short AT[48 * SATW];
  __shared__ __align__(16) unsigned short OT[128 * 72];

  {
    const int r2 = tid >> 1, hh = (tid & 1) * 16;
    const size_t wo = (size_t)(obase + r2) * HID + hh;
    *(bf16x8*)(&W2Hs[r2 * 40 + hh]) = *(const bf16x8*)(&w2H[wo]);
    *(bf16x8*)(&W2Hs[r2 * 40 + hh + 8]) = *(const bf16x8*)(&w2H[wo + 8]);
    *(bf16x8*)(&W2Ls[r2 * 40 + hh]) = *(const bf16x8*)(&w2L[wo]);
    *(bf16x8*)(&W2Ls[r2 * 40 + hh + 8]) = *(const bf16x8*)(&w2L[wo + 8]);
  }
  {
    const int h = tid >> 3, seg16 = (tid & 7) * 16;
#pragma unroll
    for (int j = 0; j < 2; ++j) {
      const int seg = seg16 + 8 * j;
      *(bf16x8*)(&AT[h * SATW + seg]) =
          *(const bf16x8*)(&actT[(size_t)h * BATCH + b0 + seg]);
    }
  }
  for (int e = tid; e < 16 * SATW; e += 256)
    AT[32 * SATW + e] = (unsigned short)0x3F80;

  f32x4 c0a = {0.f,0.f,0.f,0.f}, c1a = {0.f,0.f,0.f,0.f}, c2a = {0.f,0.f,0.f,0.f};
  f32x4 c0b = {0.f,0.f,0.f,0.f}, c1b = {0.f,0.f,0.f,0.f}, c2b = {0.f,0.f,0.f,0.f};

  for (int hf = 0; hf < 2; ++hf) {
    __syncthreads();
    {
      const int b = tid >> 2, q = (tid & 3) * 8;
      *(bf16x8*)(&AH[b * 40 + q]) =
          *(const bf16x8*)(&actH[(size_t)(b0 + 64 * hf + b) * HID + q]);
      *(bf16x8*)(&AL[b * 40 + q]) =
          *(const bf16x8*)(&actL[(size_t)(b0 + 64 * hf + b) * HID + q]);
    }
    __syncthreads();

    const int bt = wv;
    bf16x8 fah = *(const bf16x8*)(&AH[(bt * 16 + arow) * 40 + ksub]);
    bf16x8 fal = *(const bf16x8*)(&AL[(bt * 16 + arow) * 40 + ksub]);
#pragma unroll
    for (int ot = 0; ot < 8; ++ot) {
      bf16x8 wbh = *(const bf16x8*)(&W2Hs[(ot * 16 + arow) * 40 + ksub]);
      bf16x8 wbl = *(const bf16x8*)(&W2Ls[(ot * 16 + arow) * 40 + ksub]);
      f32x4 z = {0.f, 0.f, 0.f, 0.f};
      z = __builtin_amdgcn_mfma_f32_16x16x32_bf16(fah, wbh, z, 0, 0, 0);
      z = __builtin_amdgcn_mfma_f32_16x16x32_bf16(fah, wbl, z, 0, 0, 0);
      z = __builtin_amdgcn_mfma_f32_16x16x32_bf16(fal, wbh, z, 0, 0, 0);
      ushort4 po;
      {
        float ov0 = 1.0f / (1.0f + __expf(-z[0])) - 0.4f;
        float ov1 = 1.0f / (1.0f + __expf(-z[1])) - 0.4f;
        float ov2 = 1.0f / (1.0f + __expf(-z[2])) - 0.4f;
        float ov3 = 1.0f / (1.0f + __expf(-z[3])) - 0.4f;
        const size_t ob = (size_t)(b0 + 64 * hf + bt * 16 + m4 * 4) * OUTD +
                          obase + ot * 16 + arow;
        out[ob + 0 * OUTD] = ov0;
        out[ob + 1 * OUTD] = ov1;
        out[ob + 2 * OUTD] = ov2;
        out[ob + 3 * OUTD] = ov3;
        po.x = f2bf(ov0); po.y = f2bf(ov1); po.z = f2bf(ov2); po.w = f2bf(ov3);
      }
      *(ushort4*)(&OT[(ot * 16 + arow) * 72 + bt * 16 + m4 * 4]) = po;
    }
    __syncthreads();

    {
      const int ot = wv * 2;
#pragma unroll
      for (int ks = 0; ks < 2; ++ks) {
        const int bb = ks * 32 + ksub;
        const int bb2 = 64 * hf + bb;
        bf16x8 bo = *(const bf16x8*)(&OT[(ot * 16 + arow) * 72 + bb]);
        bf16x8 a0 = *(const bf16x8*)(&AT[arow * SATW + bb2]);
        bf16x8 a1 = *(const bf16x8*)(&AT[(16 + arow) * SATW + bb2]);
        bf16x8 a2 = *(const bf16x8*)(&AT[(32 + arow) * SATW + bb2]);
        c0a = __builtin_amdgcn_mfma_f32_16x16x32_bf16(a0, bo, c0a, 0, 0, 0);
        c1a = __builtin_amdgcn_mfma_f32_16x16x32_bf16(a1, bo, c1a, 0, 0, 0);
        c2a = __builtin_amdgcn_mfma_f32_16x16x32_bf16(a2, bo, c2a, 0, 0, 0);
      }
    }
    {
      const int ot = wv * 2 + 1;
#pragma unroll
      for (int ks = 0; ks < 2; ++ks) {
        const int bb = ks * 32 + ksub;
        const int bb2 = 64 * hf + bb;
        bf16x8 bo = *(const bf16x8*)(&OT[(ot * 16 + arow) * 72 + bb]);
        bf16x8 a0 = *(const bf16x8*)(&AT[arow * SATW + bb2]);
        bf16x8 a1 = *(const bf16x8*)(&AT[(16 + arow) * SATW + bb2]);
        bf16x8 a2 = *(const bf16x8*)(&AT[(32 + arow) * SATW + bb2]);
        c0b = __builtin_amdgcn_mfma_f32_16x16x32_bf16(a0, bo, c0b, 0, 0, 0);
        c1b = __builtin_amdgcn_mfma_f32_16x16x32_bf16(a1, bo, c1b, 0, 0, 0);
        c2b = __builtin_amdgcn_mfma_f32_16x16x32_bf16(a2, bo, c2b, 0, 0, 0);
      }
    }
  }

  {
    const int ot0 = wv * 2, ot1 = wv * 2 + 1;
    float* cp0 = corr2_part + (size_t)bc * (HID * OUTD) + obase + ot0 * 16 + arow;
    float* cp1 = corr2_part + (size_t)bc * (HID * OUTD) + obase + ot1 * 16 + arow;
#pragma unroll
    for (int r = 0; r < 4; ++r) {
      cp0[(size_t)(m4 * 4 + r) * OUTD] = c0a[r];
      cp0[(size_t)(16 + m4 * 4 + r) * OUTD] = c1a[r];
      cp1[(size_t)(m4 * 4 + r) * OUTD] = c0b[r];
      cp1[(size_t)(16 + m4 * 4 + r) * OUTD] = c1b[r];
    }
    if (m4 == 0) {
      outsum_part[(size_t)bc * OUTD + obase + ot0 * 16 + arow] = c2a[0];
      outsum_part[(size_t)bc * OUTD + obase + ot1 * 16 + arow] = c2b[0];
    }
  }
}

// ---------------------------------------------------------------------------
// K3b: deterministic reduce of corr2/outsum partials (128 slices).
// ---------------------------------------------------------------------------
__global__ __launch_bounds__(256) void k_red2(
    const float* __restrict__ corr2_part, const float* __restrict__ outsum_part,
    float* __restrict__ corr2, float* __restrict__ outsum) {
  const int e = blockIdx.x * 256 + threadIdx.x;
  float s = 0.f;
#pragma unroll 8
  for (int c = 0; c < NC2; ++c) s += corr2_part[(size_t)c * (HID * OUTD) + e];
  corr2[e] = s;
  if (e < OUTD) {
    float t = 0.f;
#pragma unroll 8
    for (int c = 0; c < NC2; ++c) t += outsum_part[(size_t)c * OUTD + e];
    outsum[e] = t;
  }
}

// ---------------------------------------------------------------------------
// K4: w1_new[h,i] = (w1[h,i] + dw1T[i,h]) / ||row h||_2 ; corr1T[h][i].
// ---------------------------------------------------------------------------
__global__ __launch_bounds__(256) void k_w1(
    const float* __restrict__ w1, const float* __restrict__ heb,
    const float* __restrict__ corr1T, const float* __restrict__ xsum,
    const float* __restrict__ actsum, float* __restrict__ w1out) {
  const int h = blockIdx.x;
  const int tid = threadIdx.x;
  const float ash = actsum[h];
  const float4* heb4 = (const float4*)heb;

  float val[8];
  float ss = 0.f;
#pragma unroll
  for (int r = 0; r < 8; ++r) {
    const int i = tid + 256 * r;
    float4 c = heb4[(size_t)i * HID + h];
    float v = w1[(size_t)h * IND + i] + 16384.0f * c.w +
              c.x * corr1T[(size_t)h * IND + i] + c.y * xsum[i] + c.z * ash;
    val[r] = v;
    ss += v * v;
  }

  __shared__ float red[256];
  red[tid] = ss;
  __syncthreads();
  for (int s = 128; s > 0; s >>= 1) {
    if (tid < s) red[tid] += red[tid + s];
    __syncthreads();
  }
  const float inv = 1.0f / sqrtf(red[0]);
#pragma unroll
  for (int r = 0; r < 8; ++r) {
    const int i = tid + 256 * r;
    w1out[(size_t)h * IND + i] = val[r] * inv;
  }
}

// ---------------------------------------------------------------------------
// K5: w2_new[o,h] = (w2[o,h] + dw2T[h,o]) / ||row o||_2
// ---------------------------------------------------------------------------
__global__ __launch_bounds__(256) void k_w2(
    const float* __restrict__ w2, const float* __restrict__ heb,
    const float* __restrict__ corr2, const float* __restrict__ actsum,
    const float* __restrict__ outsum, float* __restrict__ w2out) {
  const int o = blockIdx.x * 256 + threadIdx.x;
  const float oso = outsum[o];
  const float4* heb4 = (const float4*)heb;

  float val[HID];
  float ss = 0.f;
#pragma unroll
  for (int h = 0; h < HID; ++h) {
    float4 c = heb4[(size_t)(HID * IND) + (size_t)h * OUTD + o];
    float v = w2[(size_t)o * HID + h] + 16384.0f * c.w +
              c.x * corr2[(size_t)h * OUTD + o] + c.y * actsum[h] + c.z * oso;
    val[h] = v;
    ss += v * v;
  }
  const float inv = 1.0f / sqrtf(ss);
#pragma unroll
  for (int h = 0; h < HID; ++h) w2out[(size_t)o * HID + h] = val[h] * inv;
}

// ---------------------------------------------------------------------------
extern "C" void kernel_launch(void* const* d_in, const int* in_sizes, int n_in,
                              void* d_out, int out_size, void* d_ws,
                              size_t ws_size, hipStream_t stream) {
  const float* x   = (const float*)d_in[0];   // [16384, 2048]
  const float* w1  = (const float*)d_in[1];   // [32, 2048]
  const float* w2  = (const float*)d_in[2];   // [512, 32]
  const float* heb = (const float*)d_in[3];   // [81920, 4]

  float* out = (float*)d_out;                 // [16384, 512]
  float* w1o = out + (size_t)BATCH * OUTD;    // [32, 2048]
  float* w2o = w1o + (size_t)HID * IND;       // [512, 32]

  float* ws = (float*)d_ws;                   // ws ~537 MB; layout ~110 MB
  unsigned short* actH = (unsigned short*)ws;                      // 262144 f
  unsigned short* actL = actH + (size_t)BATCH * HID;               // 262144 f
  unsigned short* actT = actL + (size_t)BATCH * HID;               // 262144 f
  unsigned short* w1H  = actT + (size_t)BATCH * HID;               // 32768 f
  unsigned short* w1L  = w1H + (size_t)HID * IND;                  // 32768 f
  unsigned short* w2H  = w1L + (size_t)HID * IND;                  // 8192 f
  unsigned short* w2L  = w2H + (size_t)OUTD * HID;                 // 8192 f
  unsigned short* xH   = w2L + (size_t)OUTD * HID;                 // 16.8M f
  float* corr1T      = (float*)(xH + (size_t)BATCH * IND);         // 65536
  float* corr2       = corr1T + (size_t)IND * HID;                 // 16384
  float* xsum        = corr2 + (size_t)HID * OUTD;                 // 2048
  float* actsum      = xsum + IND;                                 // 32
  float* outsum      = actsum + HID;                               // 512
  float* act_part    = outsum + OUTD;                              // 2*524288
  float* corr1T_part = act_part + (size_t)2 * BATCH * HID;         // 64*65536
  float* xsum_part   = corr1T_part + (size_t)NC1 * IND * HID;      // 64*2048
  float* actsum_part = xsum_part + (size_t)NC1 * IND;              // 64*32
  float* corr2_part  = actsum_part + (size_t)NSA * HID;            // 128*16384
  float* outsum_part = corr2_part + (size_t)NC2 * HID * OUTD;      // 128*512

  k_cvtw <<<80, 256, 0, stream>>>(w1, w2, w1H, w1L, w2H, w2L);
  k_act  <<<1024, 256, 0, stream>>>(x, w1H, w1L, act_part, xH);
  k_actc <<<64, 256, 0, stream>>>(act_part, actH, actL, actT, actsum_part);
  k_corr1<<<1024, 512, 0, stream>>>(xH, actT, corr1T_part, xsum_part);
  k_red1 <<<256, 256, 0, stream>>>(corr1T_part, xsum_part, actsum_part,
                                   corr1T, xsum, actsum);
  k_fwd2m<<<512, 256, 0, stream>>>(actH, actL, actT, w2H, w2L, out,
                                   corr2_part, outsum_part);
  k_red2 <<<64, 256, 0, stream>>>(corr2_part, outsum_part, corr2, outsum);
  k_w1   <<<32, 256, 0, stream>>>(w1, heb, corr1T, xsum, actsum, w1o);
  k_w2   <<<2, 256, 0, stream>>>(w2, heb, corr2, actsum, outsum, w2o);
}